// Round 8
// baseline (2042.990 us; speedup 1.0000x reference)
//
#include <hip/hip_runtime.h>
#include <hip/hip_fp16.h>
#include <cstdint>

#define IN_DIM   128
#define HIDC     64
#define HEADS    4
#define OUT_DIM  40
#define NEG_SLOPE 0.2f
#define BN_EPS   1e-5f

typedef unsigned short ushortt;
typedef float fx4 __attribute__((ext_vector_type(4)));

__device__ __forceinline__ float bfval(ushortt u) {
    return __uint_as_float(((unsigned)u) << 16);
}
__device__ __forceinline__ ushortt f2bf(float f) {
    unsigned u = __float_as_uint(f);
    u += 0x7fffu + ((u >> 16) & 1u);
    return (ushortt)(u >> 16);
}
__device__ __forceinline__ unsigned pack2bf(float a, float b) {
    return (unsigned)f2bf(a) | ((unsigned)f2bf(b) << 16);
}
__device__ __forceinline__ void nt_store4(float* p, float a, float b, float c, float d) {
    fx4 v = {a, b, c, d};
    __builtin_nontemporal_store(v, (fx4*)p);
}

// acc[0..7] += a * bf16x8(h)
__device__ __forceinline__ void acc8(float* acc, float a, uint4 h) {
    unsigned u;
    u = h.x;
    acc[0] = fmaf(a, __uint_as_float(u << 16), acc[0]);
    acc[1] = fmaf(a, __uint_as_float(u & 0xffff0000u), acc[1]);
    u = h.y;
    acc[2] = fmaf(a, __uint_as_float(u << 16), acc[2]);
    acc[3] = fmaf(a, __uint_as_float(u & 0xffff0000u), acc[3]);
    u = h.z;
    acc[4] = fmaf(a, __uint_as_float(u << 16), acc[4]);
    acc[5] = fmaf(a, __uint_as_float(u & 0xffff0000u), acc[5]);
    u = h.w;
    acc[6] = fmaf(a, __uint_as_float(u << 16), acc[6]);
    acc[7] = fmaf(a, __uint_as_float(u & 0xffff0000u), acc[7]);
}

// ---------------- CSR build ----------------
__global__ void detect_kernel(const unsigned int* __restrict__ e, int* __restrict__ flag) {
    __shared__ int any;
    if (threadIdx.x == 0) any = 0;
    __syncthreads();
    for (int i = threadIdx.x; i < 1024; i += 256)
        if (e[2 * i + 1] != 0u) any = 1;
    __syncthreads();
    if (threadIdx.x == 0) flag[0] = any ? 0 : 1;   // 1 => int64
}

__device__ __forceinline__ int load_idx(const int* ei, int is64, long long pos) {
    return is64 ? ei[2 * pos] : ei[pos];
}

__global__ void hist_kernel(const int* __restrict__ ei, const int* __restrict__ flag,
                            int* __restrict__ deg, int E, int Etot) {
    int i = blockIdx.x * 256 + threadIdx.x;
    if (i >= Etot) return;
    int is64 = flag[0];
    int dst = (i < E) ? load_idx(ei, is64, (long long)E + i) : (i - E);
    atomicAdd(&deg[dst], 1);
}

__global__ void scan_kernel(int* __restrict__ data, int n) {
    __shared__ int wsum[16];
    __shared__ int chunk_total;
    int lane = threadIdx.x & 63;
    int w = threadIdx.x >> 6;
    int carry = 0;
    for (int base = 0; base < n; base += 1024) {
        int i = base + (int)threadIdx.x;
        int v = (i < n) ? data[i] : 0;
        int x = v;
        #pragma unroll
        for (int ofs = 1; ofs < 64; ofs <<= 1) {
            int y = __shfl_up(x, ofs);
            if (lane >= ofs) x += y;
        }
        if (lane == 63) wsum[w] = x;
        __syncthreads();
        if (w == 0) {
            int s = (lane < 16) ? wsum[lane] : 0;
            #pragma unroll
            for (int ofs = 1; ofs < 16; ofs <<= 1) {
                int y = __shfl_up(s, ofs);
                if (lane >= ofs) s += y;
            }
            if (lane < 16) wsum[lane] = s;
            if (lane == 15) chunk_total = s;
        }
        __syncthreads();
        int woff = (w > 0) ? wsum[w - 1] : 0;
        if (i < n) data[i] = (x + woff) - v + carry;
        int ct = chunk_total;
        __syncthreads();
        carry += ct;
    }
}

__global__ void scatter_kernel(const int* __restrict__ ei, const int* __restrict__ flag,
                               int* __restrict__ cursor, int* __restrict__ csr,
                               int E, int Etot) {
    int i = blockIdx.x * 256 + threadIdx.x;
    if (i >= Etot) return;
    int is64 = flag[0];
    int src, dst;
    if (i < E) {
        src = load_idx(ei, is64, i);
        dst = load_idx(ei, is64, (long long)E + i);
    } else {
        src = dst = i - E;
    }
    int pos = atomicAdd(&cursor[dst], 1);
    csr[pos] = src;
}

// ---------------- fold bias+BN into scale/shift ----------------
__global__ void prep_bn_kernel(const float* b1, const float* g1, const float* bb1,
                               const float* m1, const float* v1,
                               const float* b2, const float* g2, const float* bb2,
                               const float* m2, const float* v2,
                               float* __restrict__ bnsc, float* __restrict__ bnsh) {
    int t = threadIdx.x;
    if (t < 256) {
        float s = g1[t] * rsqrtf(v1[t] + BN_EPS);
        bnsc[t] = s;
        bnsh[t] = (b1[t] - m1[t]) * s + bb1[t];
    } else if (t < 320) {
        int c = t - 256;
        float s = g2[c] * rsqrtf(v2[c] + BN_EPS);
        bnsc[t] = s;
        bnsh[t] = (b2[c] - m2[c]) * s + bb2[c];
    }
}

// ---------------- register-tiled fp32 GEMM -> bf16 output ----------------
template <int K, int BN, int TN, int NC, int LDW>
__launch_bounds__(256)
__global__ void gemm_tiled_kernel(const float* __restrict__ A, const float* __restrict__ W,
                                  ushortt* __restrict__ hB, int M, int nstride) {
    __shared__ float Al[8][128];
    __shared__ float Wl[8][BN];
    int m0 = blockIdx.x * 128;
    int n0 = blockIdx.y * BN;
    int t = threadIdx.x;
    int tm = t >> 4, tn = t & 15;
    float acc[8][TN] = {};
    int r = t >> 1, kq = (t & 1) * 4;

    for (int k0 = 0; k0 < K; k0 += 8) {
        float4 av = make_float4(0.f, 0.f, 0.f, 0.f);
        if (m0 + r < M) av = *(const float4*)&A[(size_t)(m0 + r) * K + k0 + kq];
        Al[kq + 0][r] = av.x; Al[kq + 1][r] = av.y;
        Al[kq + 2][r] = av.z; Al[kq + 3][r] = av.w;
        if constexpr (BN == 128) {
            int kk = t >> 5, c4 = (t & 31) * 4;
            *(float4*)&Wl[kk][c4] = *(const float4*)&W[(size_t)(k0 + kk) * LDW + n0 + c4];
        } else {
            int kk = t >> 5, c2 = (t & 31) * 2;
            float2 wv = make_float2(0.f, 0.f);
            if (c2 + 2 <= NC) wv = *(const float2*)&W[(size_t)(k0 + kk) * LDW + n0 + c2];
            *(float2*)&Wl[kk][c2] = wv;
        }
        __syncthreads();
        #pragma unroll
        for (int k = 0; k < 8; ++k) {
            float4 a0 = *(const float4*)&Al[k][tm * 8];
            float4 a1 = *(const float4*)&Al[k][tm * 8 + 4];
            float aa[8] = {a0.x, a0.y, a0.z, a0.w, a1.x, a1.y, a1.z, a1.w};
            if constexpr (TN == 8) {
                float4 w0 = *(const float4*)&Wl[k][tn * 4];
                float4 w1 = *(const float4*)&Wl[k][64 + tn * 4];
                float ww[8] = {w0.x, w0.y, w0.z, w0.w, w1.x, w1.y, w1.z, w1.w};
                #pragma unroll
                for (int i = 0; i < 8; ++i)
                    #pragma unroll
                    for (int j = 0; j < 8; ++j)
                        acc[i][j] = fmaf(aa[i], ww[j], acc[i][j]);
            } else {
                float4 w0 = *(const float4*)&Wl[k][tn * 4];
                float ww[4] = {w0.x, w0.y, w0.z, w0.w};
                #pragma unroll
                for (int i = 0; i < 8; ++i)
                    #pragma unroll
                    for (int j = 0; j < 4; ++j)
                        acc[i][j] = fmaf(aa[i], ww[j], acc[i][j]);
            }
        }
        __syncthreads();
    }
    #pragma unroll
    for (int i = 0; i < 8; ++i) {
        int m = m0 + tm * 8 + i;
        if (m >= M) continue;
        ushortt* row = hB + (size_t)m * nstride + n0;
        if constexpr (TN == 8) {
            *(uint2*)(row + tn * 4) = make_uint2(pack2bf(acc[i][0], acc[i][1]),
                                                 pack2bf(acc[i][2], acc[i][3]));
            *(uint2*)(row + 64 + tn * 4) = make_uint2(pack2bf(acc[i][4], acc[i][5]),
                                                      pack2bf(acc[i][6], acc[i][7]));
        } else {
            *(uint2*)(row + tn * 4) = make_uint2(pack2bf(acc[i][0], acc[i][1]),
                                                 pack2bf(acc[i][2], acc[i][3]));
        }
    }
}

// ---------------- attention dots from bf16 h, layer1 (4 heads): wave=node ----------------
__launch_bounds__(256)
__global__ void attn_dot1_kernel(const ushortt* __restrict__ hB,
                                 const float* __restrict__ atts, const float* __restrict__ attd,
                                 float* __restrict__ a_s4, float* __restrict__ a_d4, int N) {
    int node = blockIdx.x * 4 + (threadIdx.x >> 6);
    int lane = threadIdx.x & 63;
    if (node >= N) return;
    int c0 = lane * 4;
    uint2 u = *(const uint2*)(hB + (size_t)node * 256 + c0);
    float h0 = __uint_as_float(u.x << 16);
    float h1 = __uint_as_float(u.x & 0xffff0000u);
    float h2 = __uint_as_float(u.y << 16);
    float h3 = __uint_as_float(u.y & 0xffff0000u);
    float ps = h0 * atts[c0] + h1 * atts[c0 + 1] + h2 * atts[c0 + 2] + h3 * atts[c0 + 3];
    float pd = h0 * attd[c0] + h1 * attd[c0 + 1] + h2 * attd[c0 + 2] + h3 * attd[c0 + 3];
    #pragma unroll
    for (int o = 1; o < 16; o <<= 1) {
        ps += __shfl_xor(ps, o);
        pd += __shfl_xor(pd, o);
    }
    if ((lane & 15) == 0) {
        int head = lane >> 4;
        a_s4[(size_t)node * 4 + head] = ps;
        a_d4[(size_t)node * 4 + head] = pd;
    }
}

// ---------------- attention dots, layers 2/3 (rows stride 64): wave=node ----------------
template <int NC>
__launch_bounds__(256)
__global__ void attn_dot23_kernel(const ushortt* __restrict__ hB,
                                  const float* __restrict__ atts, const float* __restrict__ attd,
                                  float* __restrict__ a_s, float* __restrict__ a_d, int N) {
    int node = blockIdx.x * 4 + (threadIdx.x >> 6);
    int lane = threadIdx.x & 63;
    if (node >= N) return;
    float h = bfval(hB[(size_t)node * 64 + lane]);
    float as = (lane < NC) ? atts[lane] : 0.f;
    float ad = (lane < NC) ? attd[lane] : 0.f;
    float ps = h * as, pd = h * ad;
    #pragma unroll
    for (int o = 32; o; o >>= 1) {
        ps += __shfl_xor(ps, o);
        pd += __shfl_xor(pd, o);
    }
    if (lane == 0) { a_s[node] = ps; a_d[node] = pd; }
}

// ---------------- alpha layer 1 (4 heads): ONE gather walk + sequential exp walk ----------------
__launch_bounds__(256)
__global__ void alpha4_kernel(const int* __restrict__ off, const int* __restrict__ csr,
                              const float* __restrict__ a_s4, const float* __restrict__ a_d4,
                              __half* __restrict__ al4, float* __restrict__ invb, int N) {
    int node = blockIdx.x;
    if (node >= N) return;
    int head = threadIdx.x >> 6, lane = threadIdx.x & 63;
    int beg = off[node], end = off[node + 1];
    float ad = a_d4[(size_t)node * 4 + head];
    float m = -INFINITY;
    for (int j = beg + lane; j < end; j += 64) {
        float v = a_s4[(size_t)csr[j] * 4 + head] + ad;
        v = v > 0.f ? v : NEG_SLOPE * v;
        al4[(size_t)j * 4 + head] = __float2half(v);
        m = fmaxf(m, v);
    }
    #pragma unroll
    for (int o = 32; o; o >>= 1) m = fmaxf(m, __shfl_xor(m, o));
    float ss = 0.f;
    for (int j = beg + lane; j < end; j += 64) {
        float v = __half2float(al4[(size_t)j * 4 + head]);
        float e = __expf(v - m);
        al4[(size_t)j * 4 + head] = __float2half(e);
        ss += e;
    }
    #pragma unroll
    for (int o = 32; o; o >>= 1) ss += __shfl_xor(ss, o);
    if (lane == 0) invb[(size_t)node * 4 + head] = 1.f / (ss + 1e-16f);
}

// ---------------- alpha single head: same 2-walk scheme, wave=node ----------------
__launch_bounds__(256)
__global__ void alpha1w_kernel(const int* __restrict__ off, const int* __restrict__ csr,
                               const float* __restrict__ a_s, const float* __restrict__ a_d,
                               __half* __restrict__ al, float* __restrict__ invb, int N) {
    int node = blockIdx.x * 4 + (threadIdx.x >> 6);
    int lane = threadIdx.x & 63;
    if (node >= N) return;
    int beg = off[node], end = off[node + 1];
    float ad = a_d[node];
    float m = -INFINITY;
    for (int j = beg + lane; j < end; j += 64) {
        float v = a_s[csr[j]] + ad;
        v = v > 0.f ? v : NEG_SLOPE * v;
        al[j] = __float2half(v);
        m = fmaxf(m, v);
    }
    #pragma unroll
    for (int o = 32; o; o >>= 1) m = fmaxf(m, __shfl_xor(m, o));
    float ss = 0.f;
    for (int j = beg + lane; j < end; j += 64) {
        float v = __half2float(al[j]);
        float e = __expf(v - m);
        al[j] = __float2half(e);
        ss += e;
    }
    #pragma unroll
    for (int o = 32; o; o >>= 1) ss += __shfl_xor(ss, o);
    if (lane == 0) invb[node] = 1.f / (ss + 1e-16f);
}

// ---------------- PV layer 1, XCD-pinned channel chunks ----------------
// chunk = blockIdx&7 -> XCD (blocks round-robin XCDs). Chunk covers 16 ch
// (PHASE*128 + chunk*16): per-XCD gather slice = N*16*2B = 3.2MB < 4MB L2.
// Wave = node; 2 lanes/edge (16B each), 32 edges/step.
template <int PHASE>
__launch_bounds__(256)
__global__ void pv1c_kernel(const int* __restrict__ off, const int* __restrict__ csr,
                            const __half* __restrict__ al4, const ushortt* __restrict__ hB,
                            const float* __restrict__ invb,
                            const float* __restrict__ bnsc, const float* __restrict__ bnsh,
                            float* __restrict__ act, int N) {
    int chunk = blockIdx.x & 7;
    int node = (blockIdx.x >> 3) * 4 + (threadIdx.x >> 6);
    int lane = threadIdx.x & 63;
    if (node >= N) return;
    int slot = lane >> 1, half16 = lane & 1;
    int cbase = PHASE * 128 + chunk * 16;
    int head = cbase >> 6;
    unsigned coffb = (unsigned)((cbase + half16 * 8) * 2);
    unsigned hoffb = (unsigned)(head * 2);
    int beg = off[node], end = off[node + 1];
    const char* hBb = (const char*)hB;
    const char* alb = (const char*)al4;
    float acc[8] = {};
    for (int j0 = beg; j0 < end; j0 += 32) {
        int j = j0 + slot;
        bool v = j < end;
        int idx = v ? j : beg;
        int s = csr[idx];
        float a = v ? __half2float(*(const __half*)(alb + (unsigned)idx * 8u + hoffb)) : 0.f;
        uint4 h = *(const uint4*)(hBb + (unsigned)s * 512u + coffb);
        acc8(acc, a, h);
    }
    #pragma unroll
    for (int o = 2; o <= 32; o <<= 1) {
        #pragma unroll
        for (int i = 0; i < 8; ++i) acc[i] += __shfl_xor(acc[i], o);
    }
    if (lane < 2) {
        float inv = invb[(size_t)node * 4 + head];
        int g = cbase + lane * 8;
        float o[8];
        #pragma unroll
        for (int i = 0; i < 8; ++i) {
            float v = acc[i] * inv * bnsc[g + i] + bnsh[g + i];
            o[i] = v > 0.f ? v : expm1f(v);
        }
        float* dst = &act[(size_t)node * 256 + g];
        nt_store4(dst, o[0], o[1], o[2], o[3]);
        nt_store4(dst + 4, o[4], o[5], o[6], o[7]);
    }
}

// ---------------- PV layer 2, XCD-pinned chunks: 8 chunks x 8 ch (1.6MB/XCD slice) ----------------
// Wave = node; 1 lane/edge (16B), 64 edges/step. BN+ELU epilogue -> act[node][64].
__launch_bounds__(256)
__global__ void pv2c_kernel(const int* __restrict__ off, const int* __restrict__ csr,
                            const __half* __restrict__ al, const ushortt* __restrict__ hB,
                            const float* __restrict__ invb,
                            const float* __restrict__ bnsc, const float* __restrict__ bnsh,
                            float* __restrict__ act, int N) {
    int chunk = blockIdx.x & 7;
    int node = (blockIdx.x >> 3) * 4 + (threadIdx.x >> 6);
    int lane = threadIdx.x & 63;
    if (node >= N) return;
    unsigned coffb = (unsigned)(chunk * 16);
    int beg = off[node], end = off[node + 1];
    const char* hBb = (const char*)hB;
    float acc[8] = {};
    for (int j0 = beg; j0 < end; j0 += 64) {
        int j = j0 + lane;
        bool v = j < end;
        int idx = v ? j : beg;
        int s = csr[idx];
        float a = v ? __half2float(al[idx]) : 0.f;
        uint4 h = *(const uint4*)(hBb + (unsigned)s * 128u + coffb);
        acc8(acc, a, h);
    }
    #pragma unroll
    for (int o = 1; o <= 32; o <<= 1) {
        #pragma unroll
        for (int i = 0; i < 8; ++i) acc[i] += __shfl_xor(acc[i], o);
    }
    if (lane == 0) {
        float inv = invb[node];
        int g = chunk * 8;
        float o[8];
        #pragma unroll
        for (int i = 0; i < 8; ++i) {
            float v = acc[i] * inv * bnsc[256 + g + i] + bnsh[256 + g + i];
            o[i] = v > 0.f ? v : expm1f(v);
        }
        float* dst = &act[(size_t)node * 64 + g];
        nt_store4(dst, o[0], o[1], o[2], o[3]);
        nt_store4(dst + 4, o[4], o[5], o[6], o[7]);
    }
}

// ---------------- PV layer 3 (unchunked): wave=node, 8 lanes/edge; fused bias+log_softmax ----------------
__launch_bounds__(256)
__global__ void pv3_kernel(const int* __restrict__ off, const int* __restrict__ csr,
                           const __half* __restrict__ al, const ushortt* __restrict__ hB,
                           const float* __restrict__ invb, const float* __restrict__ bias,
                           float* __restrict__ out, int N) {
    int node = blockIdx.x * 4 + (threadIdx.x >> 6);
    int lane = threadIdx.x & 63;
    if (node >= N) return;
    int grp = lane >> 3, sub = lane & 7;
    unsigned subb = (unsigned)(sub * 16);
    int beg = off[node], end = off[node + 1];
    const char* hBb = (const char*)hB;
    float acc[8] = {};
    for (int j0 = beg; j0 < end; j0 += 8) {
        int j = j0 + grp;
        bool v = j < end;
        int idx = v ? j : beg;
        int s = csr[idx];
        float a = v ? __half2float(al[idx]) : 0.f;
        uint4 h = *(const uint4*)(hBb + (unsigned)s * 128u + subb);
        acc8(acc, a, h);
    }
    #pragma unroll
    for (int i = 0; i < 8; ++i) {
        acc[i] += __shfl_xor(acc[i], 8);
        acc[i] += __shfl_xor(acc[i], 16);
        acc[i] += __shfl_xor(acc[i], 32);
    }
    float inv = invb[node];
    int g = lane * 8;
    bool act8 = lane < 5;
    float val[8];
    float mx = -INFINITY;
    #pragma unroll
    for (int i = 0; i < 8; ++i) {
        val[i] = act8 ? (acc[i] * inv + bias[act8 ? (g + i) : 0]) : -INFINITY;
        mx = fmaxf(mx, val[i]);
    }
    #pragma unroll
    for (int o = 1; o < 8; o <<= 1) mx = fmaxf(mx, __shfl_xor(mx, o));
    float se = 0.f;
    if (act8) {
        #pragma unroll
        for (int i = 0; i < 8; ++i) se += __expf(val[i] - mx);
    }
    #pragma unroll
    for (int o = 1; o < 8; o <<= 1) se += __shfl_xor(se, o);
    if (act8) {
        float lse = mx + logf(se);
        float o0[8];
        #pragma unroll
        for (int i = 0; i < 8; ++i) o0[i] = val[i] - lse;
        float* dst = &out[(size_t)node * 40 + g];
        nt_store4(dst, o0[0], o0[1], o0[2], o0[3]);
        nt_store4(dst + 4, o0[4], o0[5], o0[6], o0[7]);
    }
}

// ---------------- host ----------------
extern "C" void kernel_launch(void* const* d_in, const int* in_sizes, int n_in,
                              void* d_out, int out_size, void* d_ws, size_t ws_size,
                              hipStream_t stream) {
    const float* x      = (const float*)d_in[0];
    const int*   ei     = (const int*)d_in[1];
    const float* W1     = (const float*)d_in[2];
    const float* att_s1 = (const float*)d_in[3];
    const float* att_d1 = (const float*)d_in[4];
    const float* b1     = (const float*)d_in[5];
    const float* bn1g   = (const float*)d_in[6];
    const float* bn1b   = (const float*)d_in[7];
    const float* bn1m   = (const float*)d_in[8];
    const float* bn1v   = (const float*)d_in[9];
    const float* W2     = (const float*)d_in[10];
    const float* att_s2 = (const float*)d_in[11];
    const float* att_d2 = (const float*)d_in[12];
    const float* b2     = (const float*)d_in[13];
    const float* bn2g   = (const float*)d_in[14];
    const float* bn2b   = (const float*)d_in[15];
    const float* bn2m   = (const float*)d_in[16];
    const float* bn2v   = (const float*)d_in[17];
    const float* W3     = (const float*)d_in[18];
    const float* att_s3 = (const float*)d_in[19];
    const float* att_d3 = (const float*)d_in[20];
    const float* b3     = (const float*)d_in[21];

    const int N    = in_sizes[0] / IN_DIM;
    const int E    = in_sizes[1] / 2;
    const int Etot = E + N;

    int*   wsi = (int*)d_ws;
    float* wsf = (float*)d_ws;
    size_t p = 0;
    int*   off    = wsi + p; p += (size_t)N + 16;
    int*   cursor = wsi + p; p += (size_t)N;
    int*   flag   = wsi + p; p += 16;
    int*   csr    = wsi + p; p += (size_t)Etot;
    float* a_s    = wsf + p; p += (size_t)N * 4;
    float* a_d    = wsf + p; p += (size_t)N * 4;
    float* invb   = wsf + p; p += (size_t)N * 4;
    float* bnsc   = wsf + p; p += 384;
    float* bnsh   = wsf + p; p += 384;
    size_t H = p;            p += (size_t)N * 128;   // hB1 / hB23
    float* act    = wsf + p; p += (size_t)N * 256;
    size_t ALR = p;          p += (size_t)Etot * 2;  // al4 / al23
    if (ws_size < p * 4) return;

    ushortt* hB1  = (ushortt*)(wsf + H);
    ushortt* hB23 = (ushortt*)(wsf + H);
    __half*  al4  = (__half*)(wsf + ALR);
    __half*  al23 = (__half*)(wsf + ALR);

    float* outp = (float*)d_out;

    // ---- CSR build ----
    hipMemsetAsync(off, 0, ((size_t)N + 1) * sizeof(int), stream);
    detect_kernel<<<1, 256, 0, stream>>>((const unsigned int*)ei, flag);
    {
        int blocks = (Etot + 255) / 256;
        hist_kernel<<<blocks, 256, 0, stream>>>(ei, flag, off, E, Etot);
        scan_kernel<<<1, 1024, 0, stream>>>(off, N + 1);
        hipMemcpyAsync(cursor, off, (size_t)N * sizeof(int), hipMemcpyDeviceToDevice, stream);
        scatter_kernel<<<blocks, 256, 0, stream>>>(ei, flag, cursor, csr, E, Etot);
    }
    prep_bn_kernel<<<1, 384, 0, stream>>>(b1, bn1g, bn1b, bn1m, bn1v,
                                          b2, bn2g, bn2b, bn2m, bn2v, bnsc, bnsh);

    const int gm = (N + 127) / 128;
    const int nb4 = (N + 3) / 4;

    // ---- layer 1 ----
    gemm_tiled_kernel<128, 128, 8, 256, 256><<<dim3(gm, 2), 256, 0, stream>>>(x, W1, hB1, N, 256);
    attn_dot1_kernel<<<nb4, 256, 0, stream>>>(hB1, att_s1, att_d1, a_s, a_d, N);
    alpha4_kernel<<<N, 256, 0, stream>>>(off, csr, a_s, a_d, al4, invb, N);
    pv1c_kernel<0><<<nb4 * 8, 256, 0, stream>>>(off, csr, al4, hB1, invb, bnsc, bnsh, act, N);
    pv1c_kernel<1><<<nb4 * 8, 256, 0, stream>>>(off, csr, al4, hB1, invb, bnsc, bnsh, act, N);

    // ---- layer 2 ----
    gemm_tiled_kernel<256, 64, 4, 64, 64><<<dim3(gm, 1), 256, 0, stream>>>(act, W2, hB23, N, 64);
    attn_dot23_kernel<64><<<nb4, 256, 0, stream>>>(hB23, att_s2, att_d2, a_s, a_d, N);
    alpha1w_kernel<<<nb4, 256, 0, stream>>>(off, csr, a_s, a_d, al23, invb, N);
    pv2c_kernel<<<nb4 * 8, 256, 0, stream>>>(off, csr, al23, hB23, invb, bnsc, bnsh, act, N);

    // ---- layer 3 (log_softmax fused into PV epilogue) ----
    gemm_tiled_kernel<64, 64, 4, 40, 40><<<dim3(gm, 1), 256, 0, stream>>>(act, W3, hB23, N, 64);
    attn_dot23_kernel<40><<<nb4, 256, 0, stream>>>(hB23, att_s3, att_d3, a_s, a_d, N);
    alpha1w_kernel<<<nb4, 256, 0, stream>>>(off, csr, a_s, a_d, al23, invb, N);
    pv3_kernel<<<nb4, 256, 0, stream>>>(off, csr, al23, hB23, invb, b3, outp, N);
}

// Round 9
// 927.106 us; speedup vs baseline: 2.2036x; 2.2036x over previous
//
#include <hip/hip_runtime.h>
#include <cstdint>

#define IN_DIM   128
#define HIDC     64
#define HEADS    4
#define OUT_DIM  40
#define NEG_SLOPE 0.2f
#define BN_EPS   1e-5f

typedef unsigned short ushortt;
typedef float fx4 __attribute__((ext_vector_type(4)));

__device__ __forceinline__ float bfval(ushortt u) {
    return __uint_as_float(((unsigned)u) << 16);
}
__device__ __forceinline__ ushortt f2bf(float f) {
    unsigned u = __float_as_uint(f);
    u += 0x7fffu + ((u >> 16) & 1u);
    return (ushortt)(u >> 16);
}
__device__ __forceinline__ unsigned pack2bf(float a, float b) {
    return (unsigned)f2bf(a) | ((unsigned)f2bf(b) << 16);
}

// acc[0..7] += a * bf16x8(h)
__device__ __forceinline__ void acc8(float* acc, float a, uint4 h) {
    unsigned u;
    u = h.x;
    acc[0] = fmaf(a, __uint_as_float(u << 16), acc[0]);
    acc[1] = fmaf(a, __uint_as_float(u & 0xffff0000u), acc[1]);
    u = h.y;
    acc[2] = fmaf(a, __uint_as_float(u << 16), acc[2]);
    acc[3] = fmaf(a, __uint_as_float(u & 0xffff0000u), acc[3]);
    u = h.z;
    acc[4] = fmaf(a, __uint_as_float(u << 16), acc[4]);
    acc[5] = fmaf(a, __uint_as_float(u & 0xffff0000u), acc[5]);
    u = h.w;
    acc[6] = fmaf(a, __uint_as_float(u << 16), acc[6]);
    acc[7] = fmaf(a, __uint_as_float(u & 0xffff0000u), acc[7]);
}

// online-softmax pairwise combine
__device__ __forceinline__ void sm_combine(float& m, float& s, float mo, float so) {
    float M = fmaxf(m, mo);
    float sa = (M == -INFINITY) ? 0.f : s * __expf(m - M);
    float sb = (M == -INFINITY) ? 0.f : so * __expf(mo - M);
    m = M; s = sa + sb;
}

// ---------------- CSR build ----------------
__global__ void detect_kernel(const unsigned int* __restrict__ e, int* __restrict__ flag) {
    __shared__ int any;
    if (threadIdx.x == 0) any = 0;
    __syncthreads();
    for (int i = threadIdx.x; i < 1024; i += 256)
        if (e[2 * i + 1] != 0u) any = 1;
    __syncthreads();
    if (threadIdx.x == 0) flag[0] = any ? 0 : 1;   // 1 => int64
}

__device__ __forceinline__ int load_idx(const int* ei, int is64, long long pos) {
    return is64 ? ei[2 * pos] : ei[pos];
}

__global__ void hist_kernel(const int* __restrict__ ei, const int* __restrict__ flag,
                            int* __restrict__ deg, int E, int Etot) {
    int i = blockIdx.x * 256 + threadIdx.x;
    if (i >= Etot) return;
    int is64 = flag[0];
    int dst = (i < E) ? load_idx(ei, is64, (long long)E + i) : (i - E);
    atomicAdd(&deg[dst], 1);
}

__global__ void scan_kernel(int* __restrict__ data, int n) {
    __shared__ int wsum[16];
    __shared__ int chunk_total;
    int lane = threadIdx.x & 63;
    int w = threadIdx.x >> 6;
    int carry = 0;
    for (int base = 0; base < n; base += 1024) {
        int i = base + (int)threadIdx.x;
        int v = (i < n) ? data[i] : 0;
        int x = v;
        #pragma unroll
        for (int ofs = 1; ofs < 64; ofs <<= 1) {
            int y = __shfl_up(x, ofs);
            if (lane >= ofs) x += y;
        }
        if (lane == 63) wsum[w] = x;
        __syncthreads();
        if (w == 0) {
            int s = (lane < 16) ? wsum[lane] : 0;
            #pragma unroll
            for (int ofs = 1; ofs < 16; ofs <<= 1) {
                int y = __shfl_up(s, ofs);
                if (lane >= ofs) s += y;
            }
            if (lane < 16) wsum[lane] = s;
            if (lane == 15) chunk_total = s;
        }
        __syncthreads();
        int woff = (w > 0) ? wsum[w - 1] : 0;
        if (i < n) data[i] = (x + woff) - v + carry;
        int ct = chunk_total;
        __syncthreads();
        carry += ct;
    }
}

__global__ void scatter_kernel(const int* __restrict__ ei, const int* __restrict__ flag,
                               int* __restrict__ cursor, int* __restrict__ csr,
                               int E, int Etot) {
    int i = blockIdx.x * 256 + threadIdx.x;
    if (i >= Etot) return;
    int is64 = flag[0];
    int src, dst;
    if (i < E) {
        src = load_idx(ei, is64, i);
        dst = load_idx(ei, is64, (long long)E + i);
    } else {
        src = dst = i - E;
    }
    int pos = atomicAdd(&cursor[dst], 1);
    csr[pos] = src;
}

// ---------------- fold bias+BN into scale/shift ----------------
__global__ void prep_bn_kernel(const float* b1, const float* g1, const float* bb1,
                               const float* m1, const float* v1,
                               const float* b2, const float* g2, const float* bb2,
                               const float* m2, const float* v2,
                               float* __restrict__ bnsc, float* __restrict__ bnsh) {
    int t = threadIdx.x;
    if (t < 256) {
        float s = g1[t] * rsqrtf(v1[t] + BN_EPS);
        bnsc[t] = s;
        bnsh[t] = (b1[t] - m1[t]) * s + bb1[t];
    } else if (t < 320) {
        int c = t - 256;
        float s = g2[c] * rsqrtf(v2[c] + BN_EPS);
        bnsc[t] = s;
        bnsh[t] = (b2[c] - m2[c]) * s + bb2[c];
    }
}

// ---------------- register-tiled GEMM (A fp32 or bf16) -> bf16 output ----------------
template <int K, int BN, int TN, int NC, int LDW, bool ABF16>
__launch_bounds__(256)
__global__ void gemm_tiled_kernel(const void* __restrict__ Av, const float* __restrict__ W,
                                  ushortt* __restrict__ hB, int M, int nstride) {
    __shared__ float Al[8][128];
    __shared__ float Wl[8][BN];
    int m0 = blockIdx.x * 128;
    int n0 = blockIdx.y * BN;
    int t = threadIdx.x;
    int tm = t >> 4, tn = t & 15;
    float acc[8][TN] = {};
    int r = t >> 1, kq = (t & 1) * 4;

    for (int k0 = 0; k0 < K; k0 += 8) {
        if constexpr (ABF16) {
            const ushortt* A = (const ushortt*)Av;
            uint2 av = make_uint2(0u, 0u);
            if (m0 + r < M) av = *(const uint2*)(A + (size_t)(m0 + r) * K + k0 + kq);
            Al[kq + 0][r] = bfval((ushortt)(av.x & 0xffffu));
            Al[kq + 1][r] = bfval((ushortt)(av.x >> 16));
            Al[kq + 2][r] = bfval((ushortt)(av.y & 0xffffu));
            Al[kq + 3][r] = bfval((ushortt)(av.y >> 16));
        } else {
            const float* A = (const float*)Av;
            float4 av = make_float4(0.f, 0.f, 0.f, 0.f);
            if (m0 + r < M) av = *(const float4*)&A[(size_t)(m0 + r) * K + k0 + kq];
            Al[kq + 0][r] = av.x; Al[kq + 1][r] = av.y;
            Al[kq + 2][r] = av.z; Al[kq + 3][r] = av.w;
        }
        if constexpr (BN == 128) {
            int kk = t >> 5, c4 = (t & 31) * 4;
            *(float4*)&Wl[kk][c4] = *(const float4*)&W[(size_t)(k0 + kk) * LDW + n0 + c4];
        } else {
            int kk = t >> 5, c2 = (t & 31) * 2;
            float2 wv = make_float2(0.f, 0.f);
            if (c2 + 2 <= NC) wv = *(const float2*)&W[(size_t)(k0 + kk) * LDW + n0 + c2];
            *(float2*)&Wl[kk][c2] = wv;
        }
        __syncthreads();
        #pragma unroll
        for (int k = 0; k < 8; ++k) {
            float4 a0 = *(const float4*)&Al[k][tm * 8];
            float4 a1 = *(const float4*)&Al[k][tm * 8 + 4];
            float aa[8] = {a0.x, a0.y, a0.z, a0.w, a1.x, a1.y, a1.z, a1.w};
            if constexpr (TN == 8) {
                float4 w0 = *(const float4*)&Wl[k][tn * 4];
                float4 w1 = *(const float4*)&Wl[k][64 + tn * 4];
                float ww[8] = {w0.x, w0.y, w0.z, w0.w, w1.x, w1.y, w1.z, w1.w};
                #pragma unroll
                for (int i = 0; i < 8; ++i)
                    #pragma unroll
                    for (int j = 0; j < 8; ++j)
                        acc[i][j] = fmaf(aa[i], ww[j], acc[i][j]);
            } else {
                float4 w0 = *(const float4*)&Wl[k][tn * 4];
                float ww[4] = {w0.x, w0.y, w0.z, w0.w};
                #pragma unroll
                for (int i = 0; i < 8; ++i)
                    #pragma unroll
                    for (int j = 0; j < 4; ++j)
                        acc[i][j] = fmaf(aa[i], ww[j], acc[i][j]);
            }
        }
        __syncthreads();
    }
    #pragma unroll
    for (int i = 0; i < 8; ++i) {
        int m = m0 + tm * 8 + i;
        if (m >= M) continue;
        ushortt* row = hB + (size_t)m * nstride + n0;
        if constexpr (TN == 8) {
            *(uint2*)(row + tn * 4) = make_uint2(pack2bf(acc[i][0], acc[i][1]),
                                                 pack2bf(acc[i][2], acc[i][3]));
            *(uint2*)(row + 64 + tn * 4) = make_uint2(pack2bf(acc[i][4], acc[i][5]),
                                                      pack2bf(acc[i][6], acc[i][7]));
        } else {
            *(uint2*)(row + tn * 4) = make_uint2(pack2bf(acc[i][0], acc[i][1]),
                                                 pack2bf(acc[i][2], acc[i][3]));
        }
    }
}

// ---------------- attention dots from bf16 h, layer1 (4 heads): wave=node ----------------
__launch_bounds__(256)
__global__ void attn_dot1_kernel(const ushortt* __restrict__ hB,
                                 const float* __restrict__ atts, const float* __restrict__ attd,
                                 float* __restrict__ a_s4, float* __restrict__ a_d4, int N) {
    int node = blockIdx.x * 4 + (threadIdx.x >> 6);
    int lane = threadIdx.x & 63;
    if (node >= N) return;
    int c0 = lane * 4;
    uint2 u = *(const uint2*)(hB + (size_t)node * 256 + c0);
    float h0 = __uint_as_float(u.x << 16);
    float h1 = __uint_as_float(u.x & 0xffff0000u);
    float h2 = __uint_as_float(u.y << 16);
    float h3 = __uint_as_float(u.y & 0xffff0000u);
    float ps = h0 * atts[c0] + h1 * atts[c0 + 1] + h2 * atts[c0 + 2] + h3 * atts[c0 + 3];
    float pd = h0 * attd[c0] + h1 * attd[c0 + 1] + h2 * attd[c0 + 2] + h3 * attd[c0 + 3];
    #pragma unroll
    for (int o = 1; o < 16; o <<= 1) {
        ps += __shfl_xor(ps, o);
        pd += __shfl_xor(pd, o);
    }
    if ((lane & 15) == 0) {
        int head = lane >> 4;
        a_s4[(size_t)node * 4 + head] = ps;
        a_d4[(size_t)node * 4 + head] = pd;
    }
}

// ---------------- attention dots, layers 2/3 (rows stride 64): wave=node ----------------
template <int NC>
__launch_bounds__(256)
__global__ void attn_dot23_kernel(const ushortt* __restrict__ hB,
                                  const float* __restrict__ atts, const float* __restrict__ attd,
                                  float* __restrict__ a_s, float* __restrict__ a_d, int N) {
    int node = blockIdx.x * 4 + (threadIdx.x >> 6);
    int lane = threadIdx.x & 63;
    if (node >= N) return;
    float h = bfval(hB[(size_t)node * 64 + lane]);
    float as = (lane < NC) ? atts[lane] : 0.f;
    float ad = (lane < NC) ? attd[lane] : 0.f;
    float ps = h * as, pd = h * ad;
    #pragma unroll
    for (int o = 32; o; o >>= 1) {
        ps += __shfl_xor(ps, o);
        pd += __shfl_xor(pd, o);
    }
    if (lane == 0) { a_s[node] = ps; a_d[node] = pd; }
}

// ---------------- stats layer 1 (4 heads): ONE online walk; wave=node, lane=(edge,head) ----------------
__launch_bounds__(256)
__global__ void stats4_kernel(const int* __restrict__ off, const int* __restrict__ csr,
                              const float* __restrict__ a_s4, const float* __restrict__ a_d4,
                              float* __restrict__ mb, float* __restrict__ invb, int N) {
    int node = blockIdx.x * 4 + (threadIdx.x >> 6);
    int lane = threadIdx.x & 63;
    if (node >= N) return;
    int head = lane & 3, e16 = lane >> 2;
    int beg = off[node], end = off[node + 1];
    float ad = a_d4[(size_t)node * 4 + head];
    float m = -INFINITY, s = 0.f;
    for (int j = beg + e16; j < end; j += 16) {
        float v = a_s4[(size_t)csr[j] * 4 + head] + ad;
        v = v > 0.f ? v : NEG_SLOPE * v;
        if (v <= m) {
            s += __expf(v - m);
        } else {
            s = s * __expf(m - v) + 1.f;
            m = v;
        }
    }
    #pragma unroll
    for (int o = 4; o <= 32; o <<= 1)
        sm_combine(m, s, __shfl_xor(m, o), __shfl_xor(s, o));
    if (lane < 4) {
        mb[(size_t)node * 4 + lane] = m;
        invb[(size_t)node * 4 + lane] = 1.f / (s + 1e-16f);
    }
}

// ---------------- stats single head: ONE online walk; wave=node ----------------
__launch_bounds__(256)
__global__ void stats1_kernel(const int* __restrict__ off, const int* __restrict__ csr,
                              const float* __restrict__ a_s, const float* __restrict__ a_d,
                              float* __restrict__ mb, float* __restrict__ invb, int N) {
    int node = blockIdx.x * 4 + (threadIdx.x >> 6);
    int lane = threadIdx.x & 63;
    if (node >= N) return;
    int beg = off[node], end = off[node + 1];
    float ad = a_d[node];
    float m = -INFINITY, s = 0.f;
    for (int j = beg + lane; j < end; j += 64) {
        float v = a_s[csr[j]] + ad;
        v = v > 0.f ? v : NEG_SLOPE * v;
        if (v <= m) {
            s += __expf(v - m);
        } else {
            s = s * __expf(m - v) + 1.f;
            m = v;
        }
    }
    #pragma unroll
    for (int o = 1; o <= 32; o <<= 1)
        sm_combine(m, s, __shfl_xor(m, o), __shfl_xor(s, o));
    if (lane == 0) {
        mb[node] = m;
        invb[node] = 1.f / (s + 1e-16f);
    }
}

// ---------------- PV layer 1: wave=node, inline exp, unroll 4; bf16 act out ----------------
__launch_bounds__(256)
__global__ void pv1_kernel(const int* __restrict__ off, const int* __restrict__ csr,
                           const float* __restrict__ a_s4, const float* __restrict__ a_d4,
                           const float* __restrict__ mb, const float* __restrict__ invb,
                           const ushortt* __restrict__ hB,
                           const float* __restrict__ bnsc, const float* __restrict__ bnsh,
                           ushortt* __restrict__ actb, int N) {
    int node = blockIdx.x * 4 + (threadIdx.x >> 6);
    int lane = threadIdx.x & 63;
    if (node >= N) return;
    int half = lane >> 5, sub = lane & 31, head = sub >> 3;
    unsigned subb = (unsigned)(sub * 16);
    int beg = off[node], end = off[node + 1], deg = end - beg;
    float ad = a_d4[(size_t)node * 4 + head];
    float mh = mb[(size_t)node * 4 + head];
    const char* hBb = (const char*)hB;
    float acc[8] = {};
    int nt = (deg + 1) >> 1;
    int j = beg + half;
    int t = 0;
    for (; t + 4 <= nt; t += 4, j += 8) {
        float av[4]; unsigned ro[4];
        #pragma unroll
        for (int q = 0; q < 4; ++q) {
            int jq = j + 2 * q;
            bool v = jq < end;
            int idx = v ? jq : beg;
            int s = csr[idx];
            float vv = a_s4[(size_t)s * 4 + head] + ad;
            vv = vv > 0.f ? vv : NEG_SLOPE * vv;
            av[q] = v ? __expf(vv - mh) : 0.f;
            ro[q] = (unsigned)s * 512u + subb;
        }
        uint4 h0 = *(const uint4*)(hBb + ro[0]);
        uint4 h1 = *(const uint4*)(hBb + ro[1]);
        uint4 h2 = *(const uint4*)(hBb + ro[2]);
        uint4 h3 = *(const uint4*)(hBb + ro[3]);
        acc8(acc, av[0], h0);
        acc8(acc, av[1], h1);
        acc8(acc, av[2], h2);
        acc8(acc, av[3], h3);
    }
    for (; t < nt; ++t, j += 2) {
        bool v = j < end;
        int idx = v ? j : beg;
        int s = csr[idx];
        float vv = a_s4[(size_t)s * 4 + head] + ad;
        vv = vv > 0.f ? vv : NEG_SLOPE * vv;
        float a = v ? __expf(vv - mh) : 0.f;
        uint4 h = *(const uint4*)(hBb + (unsigned)s * 512u + subb);
        acc8(acc, a, h);
    }
    #pragma unroll
    for (int i = 0; i < 8; ++i) acc[i] += __shfl_xor(acc[i], 32);
    if (half == 0) {
        float inv = invb[(size_t)node * 4 + head];
        int g = sub * 8;
        float o[8];
        #pragma unroll
        for (int i = 0; i < 8; ++i) {
            float v = acc[i] * inv * bnsc[g + i] + bnsh[g + i];
            o[i] = v > 0.f ? v : expm1f(v);
        }
        uint4 pk = make_uint4(pack2bf(o[0], o[1]), pack2bf(o[2], o[3]),
                              pack2bf(o[4], o[5]), pack2bf(o[6], o[7]));
        *(uint4*)&actb[(size_t)node * 256 + g] = pk;
    }
}

// ---------------- PV layer 2: wave=node, 8 lanes/edge, inline exp; BN+ELU -> bf16 act2 ----------------
__launch_bounds__(256)
__global__ void pv2_kernel(const int* __restrict__ off, const int* __restrict__ csr,
                           const float* __restrict__ a_s, const float* __restrict__ a_d,
                           const float* __restrict__ mb, const float* __restrict__ invb,
                           const ushortt* __restrict__ hB,
                           const float* __restrict__ bnsc, const float* __restrict__ bnsh,
                           ushortt* __restrict__ act2b, int N) {
    int node = blockIdx.x * 4 + (threadIdx.x >> 6);
    int lane = threadIdx.x & 63;
    if (node >= N) return;
    int grp = lane >> 3, sub = lane & 7;
    unsigned subb = (unsigned)(sub * 16);
    int beg = off[node], end = off[node + 1], deg = end - beg;
    float ad = a_d[node];
    float mh = mb[node];
    const char* hBb = (const char*)hB;
    float acc[8] = {};
    int nt = (deg + 7) >> 3;
    int j = beg + grp;
    int t = 0;
    for (; t + 2 <= nt; t += 2, j += 16) {
        int jA = j, jB = j + 8;
        bool vA = jA < end, vB = jB < end;
        int iA = vA ? jA : beg, iB = vB ? jB : beg;
        int sA = csr[iA], sB = csr[iB];
        float wA = a_s[sA] + ad; wA = wA > 0.f ? wA : NEG_SLOPE * wA;
        float wB = a_s[sB] + ad; wB = wB > 0.f ? wB : NEG_SLOPE * wB;
        float aA = vA ? __expf(wA - mh) : 0.f;
        float aB = vB ? __expf(wB - mh) : 0.f;
        uint4 hA = *(const uint4*)(hBb + (unsigned)sA * 128u + subb);
        uint4 hBv = *(const uint4*)(hBb + (unsigned)sB * 128u + subb);
        acc8(acc, aA, hA);
        acc8(acc, aB, hBv);
    }
    for (; t < nt; ++t, j += 8) {
        bool v = j < end;
        int idx = v ? j : beg;
        int s = csr[idx];
        float w = a_s[s] + ad; w = w > 0.f ? w : NEG_SLOPE * w;
        float a = v ? __expf(w - mh) : 0.f;
        uint4 h = *(const uint4*)(hBb + (unsigned)s * 128u + subb);
        acc8(acc, a, h);
    }
    #pragma unroll
    for (int i = 0; i < 8; ++i) {
        acc[i] += __shfl_xor(acc[i], 8);
        acc[i] += __shfl_xor(acc[i], 16);
        acc[i] += __shfl_xor(acc[i], 32);
    }
    if (lane < 8) {
        float inv = invb[node];
        int g = lane * 8;
        float o[8];
        #pragma unroll
        for (int i = 0; i < 8; ++i) {
            float v = acc[i] * inv * bnsc[256 + g + i] + bnsh[256 + g + i];
            o[i] = v > 0.f ? v : expm1f(v);
        }
        uint4 pk = make_uint4(pack2bf(o[0], o[1]), pack2bf(o[2], o[3]),
                              pack2bf(o[4], o[5]), pack2bf(o[6], o[7]));
        *(uint4*)&act2b[(size_t)node * 64 + g] = pk;
    }
}

// ---------------- PV layer 3: wave=node, inline exp; fused bias+log_softmax -> out ----------------
__launch_bounds__(256)
__global__ void pv3_kernel(const int* __restrict__ off, const int* __restrict__ csr,
                           const float* __restrict__ a_s, const float* __restrict__ a_d,
                           const float* __restrict__ mb, const float* __restrict__ invb,
                           const ushortt* __restrict__ hB, const float* __restrict__ bias,
                           float* __restrict__ out, int N) {
    int node = blockIdx.x * 4 + (threadIdx.x >> 6);
    int lane = threadIdx.x & 63;
    if (node >= N) return;
    int grp = lane >> 3, sub = lane & 7;
    unsigned subb = (unsigned)(sub * 16);
    int beg = off[node], end = off[node + 1];
    float ad = a_d[node];
    float mh = mb[node];
    const char* hBb = (const char*)hB;
    float acc[8] = {};
    for (int j0 = beg; j0 < end; j0 += 8) {
        int j = j0 + grp;
        bool v = j < end;
        int idx = v ? j : beg;
        int s = csr[idx];
        float w = a_s[s] + ad; w = w > 0.f ? w : NEG_SLOPE * w;
        float a = v ? __expf(w - mh) : 0.f;
        uint4 h = *(const uint4*)(hBb + (unsigned)s * 128u + subb);
        acc8(acc, a, h);
    }
    #pragma unroll
    for (int i = 0; i < 8; ++i) {
        acc[i] += __shfl_xor(acc[i], 8);
        acc[i] += __shfl_xor(acc[i], 16);
        acc[i] += __shfl_xor(acc[i], 32);
    }
    float inv = invb[node];
    int g = lane * 8;
    bool act8 = lane < 5;
    float val[8];
    float mx = -INFINITY;
    #pragma unroll
    for (int i = 0; i < 8; ++i) {
        val[i] = act8 ? (acc[i] * inv + bias[act8 ? (g + i) : 0]) : -INFINITY;
        mx = fmaxf(mx, val[i]);
    }
    #pragma unroll
    for (int o = 1; o < 8; o <<= 1) mx = fmaxf(mx, __shfl_xor(mx, o));
    float se = 0.f;
    if (act8) {
        #pragma unroll
        for (int i = 0; i < 8; ++i) se += __expf(val[i] - mx);
    }
    #pragma unroll
    for (int o = 1; o < 8; o <<= 1) se += __shfl_xor(se, o);
    if (act8) {
        float lse = mx + logf(se);
        float* dst = &out[(size_t)node * 40 + g];
        fx4 v0 = {val[0] - lse, val[1] - lse, val[2] - lse, val[3] - lse};
        fx4 v1 = {val[4] - lse, val[5] - lse, val[6] - lse, val[7] - lse};
        *(fx4*)dst = v0;
        *(fx4*)(dst + 4) = v1;
    }
}

// ---------------- host ----------------
extern "C" void kernel_launch(void* const* d_in, const int* in_sizes, int n_in,
                              void* d_out, int out_size, void* d_ws, size_t ws_size,
                              hipStream_t stream) {
    const float* x      = (const float*)d_in[0];
    const int*   ei     = (const int*)d_in[1];
    const float* W1     = (const float*)d_in[2];
    const float* att_s1 = (const float*)d_in[3];
    const float* att_d1 = (const float*)d_in[4];
    const float* b1     = (const float*)d_in[5];
    const float* bn1g   = (const float*)d_in[6];
    const float* bn1b   = (const float*)d_in[7];
    const float* bn1m   = (const float*)d_in[8];
    const float* bn1v   = (const float*)d_in[9];
    const float* W2     = (const float*)d_in[10];
    const float* att_s2 = (const float*)d_in[11];
    const float* att_d2 = (const float*)d_in[12];
    const float* b2     = (const float*)d_in[13];
    const float* bn2g   = (const float*)d_in[14];
    const float* bn2b   = (const float*)d_in[15];
    const float* bn2m   = (const float*)d_in[16];
    const float* bn2v   = (const float*)d_in[17];
    const float* W3     = (const float*)d_in[18];
    const float* att_s3 = (const float*)d_in[19];
    const float* att_d3 = (const float*)d_in[20];
    const float* b3     = (const float*)d_in[21];

    const int N    = in_sizes[0] / IN_DIM;
    const int E    = in_sizes[1] / 2;
    const int Etot = E + N;

    int*   wsi = (int*)d_ws;
    float* wsf = (float*)d_ws;
    size_t p = 0;
    int*   off    = wsi + p; p += (size_t)N + 16;
    int*   cursor = wsi + p; p += (size_t)N;
    int*   flag   = wsi + p; p += 16;
    int*   csr    = wsi + p; p += (size_t)Etot;
    float* a_s    = wsf + p; p += (size_t)N * 4;
    float* a_d    = wsf + p; p += (size_t)N * 4;
    float* mbuf   = wsf + p; p += (size_t)N * 4;
    float* invb   = wsf + p; p += (size_t)N * 4;
    float* bnsc   = wsf + p; p += 384;
    float* bnsh   = wsf + p; p += 384;
    size_t H = p;            p += (size_t)N * 128;   // hB1 (N*256 bf16) / hB23 (N*64 bf16)
    size_t A1 = p;           p += (size_t)N * 128;   // actb  (N*256 bf16)
    size_t A2 = p;           p += (size_t)N * 32;    // act2b (N*64 bf16)
    if (ws_size < p * 4) return;

    ushortt* hB1   = (ushortt*)(wsf + H);
    ushortt* hB23  = (ushortt*)(wsf + H);
    ushortt* actb  = (ushortt*)(wsf + A1);
    ushortt* act2b = (ushortt*)(wsf + A2);

    float* outp = (float*)d_out;

    // ---- CSR build ----
    hipMemsetAsync(off, 0, ((size_t)N + 1) * sizeof(int), stream);
    detect_kernel<<<1, 256, 0, stream>>>((const unsigned int*)ei, flag);
    {
        int blocks = (Etot + 255) / 256;
        hist_kernel<<<blocks, 256, 0, stream>>>(ei, flag, off, E, Etot);
        scan_kernel<<<1, 1024, 0, stream>>>(off, N + 1);
        hipMemcpyAsync(cursor, off, (size_t)N * sizeof(int), hipMemcpyDeviceToDevice, stream);
        scatter_kernel<<<blocks, 256, 0, stream>>>(ei, flag, cursor, csr, E, Etot);
    }
    prep_bn_kernel<<<1, 384, 0, stream>>>(b1, bn1g, bn1b, bn1m, bn1v,
                                          b2, bn2g, bn2b, bn2m, bn2v, bnsc, bnsh);

    const int gm = (N + 127) / 128;
    const int nb4 = (N + 3) / 4;

    // ---- layer 1 ----
    gemm_tiled_kernel<128, 128, 8, 256, 256, false><<<dim3(gm, 2), 256, 0, stream>>>(x, W1, hB1, N, 256);
    attn_dot1_kernel<<<nb4, 256, 0, stream>>>(hB1, att_s1, att_d1, a_s, a_d, N);
    stats4_kernel<<<nb4, 256, 0, stream>>>(off, csr, a_s, a_d, mbuf, invb, N);
    pv1_kernel<<<nb4, 256, 0, stream>>>(off, csr, a_s, a_d, mbuf, invb, hB1, bnsc, bnsh, actb, N);

    // ---- layer 2 ----
    gemm_tiled_kernel<256, 64, 4, 64, 64, true><<<dim3(gm, 1), 256, 0, stream>>>(actb, W2, hB23, N, 64);
    attn_dot23_kernel<64><<<nb4, 256, 0, stream>>>(hB23, att_s2, att_d2, a_s, a_d, N);
    stats1_kernel<<<nb4, 256, 0, stream>>>(off, csr, a_s, a_d, mbuf, invb, N);
    pv2_kernel<<<nb4, 256, 0, stream>>>(off, csr, a_s, a_d, mbuf, invb, hB23, bnsc, bnsh, act2b, N);

    // ---- layer 3 (log_softmax fused into PV epilogue) ----
    gemm_tiled_kernel<64, 64, 4, 40, 40, true><<<dim3(gm, 1), 256, 0, stream>>>(act2b, W3, hB23, N, 64);
    attn_dot23_kernel<40><<<nb4, 256, 0, stream>>>(hB23, att_s3, att_d3, a_s, a_d, N);
    stats1_kernel<<<nb4, 256, 0, stream>>>(off, csr, a_s, a_d, mbuf, invb, N);
    pv3_kernel<<<nb4, 256, 0, stream>>>(off, csr, a_s, a_d, mbuf, invb, hB23, b3, outp, N);
}

// Round 10
// 915.129 us; speedup vs baseline: 2.2325x; 1.0131x over previous
//
#include <hip/hip_runtime.h>
#include <cstdint>

#define IN_DIM   128
#define HIDC     64
#define HEADS    4
#define OUT_DIM  40
#define NEG_SLOPE 0.2f
#define BN_EPS   1e-5f

typedef unsigned short ushortt;
typedef float fx4 __attribute__((ext_vector_type(4)));

__device__ __forceinline__ float bfval(ushortt u) {
    return __uint_as_float(((unsigned)u) << 16);
}
__device__ __forceinline__ ushortt f2bf(float f) {
    unsigned u = __float_as_uint(f);
    u += 0x7fffu + ((u >> 16) & 1u);
    return (ushortt)(u >> 16);
}
__device__ __forceinline__ unsigned pack2bf(float a, float b) {
    return (unsigned)f2bf(a) | ((unsigned)f2bf(b) << 16);
}

// acc[0..7] += a * bf16x8(h)
__device__ __forceinline__ void acc8(float* acc, float a, uint4 h) {
    unsigned u;
    u = h.x;
    acc[0] = fmaf(a, __uint_as_float(u << 16), acc[0]);
    acc[1] = fmaf(a, __uint_as_float(u & 0xffff0000u), acc[1]);
    u = h.y;
    acc[2] = fmaf(a, __uint_as_float(u << 16), acc[2]);
    acc[3] = fmaf(a, __uint_as_float(u & 0xffff0000u), acc[3]);
    u = h.z;
    acc[4] = fmaf(a, __uint_as_float(u << 16), acc[4]);
    acc[5] = fmaf(a, __uint_as_float(u & 0xffff0000u), acc[5]);
    u = h.w;
    acc[6] = fmaf(a, __uint_as_float(u << 16), acc[6]);
    acc[7] = fmaf(a, __uint_as_float(u & 0xffff0000u), acc[7]);
}

// ---------------- CSR build ----------------
__global__ void detect_kernel(const unsigned int* __restrict__ e, int* __restrict__ flag) {
    __shared__ int any;
    if (threadIdx.x == 0) any = 0;
    __syncthreads();
    for (int i = threadIdx.x; i < 1024; i += 256)
        if (e[2 * i + 1] != 0u) any = 1;
    __syncthreads();
    if (threadIdx.x == 0) flag[0] = any ? 0 : 1;   // 1 => int64
}

__device__ __forceinline__ int load_idx(const int* ei, int is64, long long pos) {
    return is64 ? ei[2 * pos] : ei[pos];
}

__global__ void hist_kernel(const int* __restrict__ ei, const int* __restrict__ flag,
                            int* __restrict__ deg, int E, int Etot) {
    int i = blockIdx.x * 256 + threadIdx.x;
    if (i >= Etot) return;
    int is64 = flag[0];
    int dst = (i < E) ? load_idx(ei, is64, (long long)E + i) : (i - E);
    atomicAdd(&deg[dst], 1);
}

__global__ void scan_kernel(int* __restrict__ data, int n) {
    __shared__ int wsum[16];
    __shared__ int chunk_total;
    int lane = threadIdx.x & 63;
    int w = threadIdx.x >> 6;
    int carry = 0;
    for (int base = 0; base < n; base += 1024) {
        int i = base + (int)threadIdx.x;
        int v = (i < n) ? data[i] : 0;
        int x = v;
        #pragma unroll
        for (int ofs = 1; ofs < 64; ofs <<= 1) {
            int y = __shfl_up(x, ofs);
            if (lane >= ofs) x += y;
        }
        if (lane == 63) wsum[w] = x;
        __syncthreads();
        if (w == 0) {
            int s = (lane < 16) ? wsum[lane] : 0;
            #pragma unroll
            for (int ofs = 1; ofs < 16; ofs <<= 1) {
                int y = __shfl_up(s, ofs);
                if (lane >= ofs) s += y;
            }
            if (lane < 16) wsum[lane] = s;
            if (lane == 15) chunk_total = s;
        }
        __syncthreads();
        int woff = (w > 0) ? wsum[w - 1] : 0;
        if (i < n) data[i] = (x + woff) - v + carry;
        int ct = chunk_total;
        __syncthreads();
        carry += ct;
    }
}

__global__ void scatter_kernel(const int* __restrict__ ei, const int* __restrict__ flag,
                               int* __restrict__ cursor, int* __restrict__ csr,
                               int E, int Etot) {
    int i = blockIdx.x * 256 + threadIdx.x;
    if (i >= Etot) return;
    int is64 = flag[0];
    int src, dst;
    if (i < E) {
        src = load_idx(ei, is64, i);
        dst = load_idx(ei, is64, (long long)E + i);
    } else {
        src = dst = i - E;
    }
    int pos = atomicAdd(&cursor[dst], 1);
    csr[pos] = src;
}

// ---------------- fold bias+BN into scale/shift ----------------
__global__ void prep_bn_kernel(const float* b1, const float* g1, const float* bb1,
                               const float* m1, const float* v1,
                               const float* b2, const float* g2, const float* bb2,
                               const float* m2, const float* v2,
                               float* __restrict__ bnsc, float* __restrict__ bnsh) {
    int t = threadIdx.x;
    if (t < 256) {
        float s = g1[t] * rsqrtf(v1[t] + BN_EPS);
        bnsc[t] = s;
        bnsh[t] = (b1[t] - m1[t]) * s + bb1[t];
    } else if (t < 320) {
        int c = t - 256;
        float s = g2[c] * rsqrtf(v2[c] + BN_EPS);
        bnsc[t] = s;
        bnsh[t] = (b2[c] - m2[c]) * s + bb2[c];
    }
}

// ---------------- register-tiled GEMM + fused attention dots -> bf16 h ----------------
// L1MODE: h stored head-major [head][node][64], a_s/a_d head-major [head*N + node].
// else:   h row-major [node][64], a_s[node], a_d[node].
template <int K, int BN, int TN, int NC, int LDW, bool ABF16, bool L1MODE>
__launch_bounds__(256)
__global__ void gemm_fused_kernel(const void* __restrict__ Av, const float* __restrict__ W,
                                  ushortt* __restrict__ hB,
                                  const float* __restrict__ atts, const float* __restrict__ attd,
                                  float* __restrict__ a_s, float* __restrict__ a_d,
                                  int M, int Nn) {
    __shared__ float Al[8][128];
    __shared__ float Wl[8][BN];
    int m0 = blockIdx.x * 128;
    int n0 = blockIdx.y * BN;
    int t = threadIdx.x;
    int tm = t >> 4, tn = t & 15;
    float acc[8][TN] = {};
    int r = t >> 1, kq = (t & 1) * 4;

    for (int k0 = 0; k0 < K; k0 += 8) {
        if constexpr (ABF16) {
            const ushortt* A = (const ushortt*)Av;
            uint2 av = make_uint2(0u, 0u);
            if (m0 + r < M) av = *(const uint2*)(A + (size_t)(m0 + r) * K + k0 + kq);
            Al[kq + 0][r] = bfval((ushortt)(av.x & 0xffffu));
            Al[kq + 1][r] = bfval((ushortt)(av.x >> 16));
            Al[kq + 2][r] = bfval((ushortt)(av.y & 0xffffu));
            Al[kq + 3][r] = bfval((ushortt)(av.y >> 16));
        } else {
            const float* A = (const float*)Av;
            float4 av = make_float4(0.f, 0.f, 0.f, 0.f);
            if (m0 + r < M) av = *(const float4*)&A[(size_t)(m0 + r) * K + k0 + kq];
            Al[kq + 0][r] = av.x; Al[kq + 1][r] = av.y;
            Al[kq + 2][r] = av.z; Al[kq + 3][r] = av.w;
        }
        if constexpr (BN == 128) {
            int kk = t >> 5, c4 = (t & 31) * 4;
            *(float4*)&Wl[kk][c4] = *(const float4*)&W[(size_t)(k0 + kk) * LDW + n0 + c4];
        } else {
            int kk = t >> 5, c2 = (t & 31) * 2;
            float2 wv = make_float2(0.f, 0.f);
            if (c2 + 2 <= NC) wv = *(const float2*)&W[(size_t)(k0 + kk) * LDW + n0 + c2];
            *(float2*)&Wl[kk][c2] = wv;
        }
        __syncthreads();
        #pragma unroll
        for (int k = 0; k < 8; ++k) {
            float4 a0 = *(const float4*)&Al[k][tm * 8];
            float4 a1 = *(const float4*)&Al[k][tm * 8 + 4];
            float aa[8] = {a0.x, a0.y, a0.z, a0.w, a1.x, a1.y, a1.z, a1.w};
            if constexpr (TN == 8) {
                float4 w0 = *(const float4*)&Wl[k][tn * 4];
                float4 w1 = *(const float4*)&Wl[k][64 + tn * 4];
                float ww[8] = {w0.x, w0.y, w0.z, w0.w, w1.x, w1.y, w1.z, w1.w};
                #pragma unroll
                for (int i = 0; i < 8; ++i)
                    #pragma unroll
                    for (int j = 0; j < 8; ++j)
                        acc[i][j] = fmaf(aa[i], ww[j], acc[i][j]);
            } else {
                float4 w0 = *(const float4*)&Wl[k][tn * 4];
                float ww[4] = {w0.x, w0.y, w0.z, w0.w};
                #pragma unroll
                for (int i = 0; i < 8; ++i)
                    #pragma unroll
                    for (int j = 0; j < 4; ++j)
                        acc[i][j] = fmaf(aa[i], ww[j], acc[i][j]);
            }
        }
        __syncthreads();
    }
    // ---- epilogue: bf16 stores + fused per-row attention dots ----
    #pragma unroll
    for (int i = 0; i < 8; ++i) {
        int m = m0 + tm * 8 + i;
        bool valid = m < M;
        if constexpr (L1MODE) {
            int h0 = n0 >> 6;
            if (valid) {
                ushortt* r0 = hB + ((size_t)h0 * Nn + m) * 64 + tn * 4;
                *(uint2*)r0 = make_uint2(pack2bf(acc[i][0], acc[i][1]),
                                         pack2bf(acc[i][2], acc[i][3]));
                ushortt* r1 = hB + ((size_t)(h0 + 1) * Nn + m) * 64 + tn * 4;
                *(uint2*)r1 = make_uint2(pack2bf(acc[i][4], acc[i][5]),
                                         pack2bf(acc[i][6], acc[i][7]));
            }
            int c0 = n0 + tn * 4, c1 = c0 + 64;
            float ps0 = acc[i][0] * atts[c0] + acc[i][1] * atts[c0 + 1]
                      + acc[i][2] * atts[c0 + 2] + acc[i][3] * atts[c0 + 3];
            float pd0 = acc[i][0] * attd[c0] + acc[i][1] * attd[c0 + 1]
                      + acc[i][2] * attd[c0 + 2] + acc[i][3] * attd[c0 + 3];
            float ps1 = acc[i][4] * atts[c1] + acc[i][5] * atts[c1 + 1]
                      + acc[i][6] * atts[c1 + 2] + acc[i][7] * atts[c1 + 3];
            float pd1 = acc[i][4] * attd[c1] + acc[i][5] * attd[c1 + 1]
                      + acc[i][6] * attd[c1 + 2] + acc[i][7] * attd[c1 + 3];
            #pragma unroll
            for (int o = 1; o < 16; o <<= 1) {
                ps0 += __shfl_xor(ps0, o); pd0 += __shfl_xor(pd0, o);
                ps1 += __shfl_xor(ps1, o); pd1 += __shfl_xor(pd1, o);
            }
            if (tn == 0 && valid) {
                a_s[(size_t)h0 * Nn + m] = ps0;
                a_s[(size_t)(h0 + 1) * Nn + m] = ps1;
                a_d[(size_t)h0 * Nn + m] = pd0;
                a_d[(size_t)(h0 + 1) * Nn + m] = pd1;
            }
        } else {
            if (valid) {
                ushortt* row = hB + (size_t)m * 64 + tn * 4;
                *(uint2*)row = make_uint2(pack2bf(acc[i][0], acc[i][1]),
                                          pack2bf(acc[i][2], acc[i][3]));
            }
            float ps = 0.f, pd = 0.f;
            #pragma unroll
            for (int j = 0; j < 4; ++j) {
                int c = tn * 4 + j;
                float as = (c < NC) ? atts[c] : 0.f;
                float ad = (c < NC) ? attd[c] : 0.f;
                ps = fmaf(acc[i][j], as, ps);
                pd = fmaf(acc[i][j], ad, pd);
            }
            #pragma unroll
            for (int o = 1; o < 16; o <<= 1) {
                ps += __shfl_xor(ps, o); pd += __shfl_xor(pd, o);
            }
            if (tn == 0 && valid) { a_s[m] = ps; a_d[m] = pd; }
        }
    }
}

// ---------------- PV layer 1: head-split, XCD-pinned (head = blockIdx&3) ----------------
// hBH head-major: [head][node][64] (128B rows). a_sH/a_dH head-major [head*N + node].
// Unnormalized online sum: acc += exp(v)*h, ssum += exp(v); normalize at end.
__launch_bounds__(256)
__global__ void pv1_kernel(const int* __restrict__ off, const int* __restrict__ csr,
                           const float* __restrict__ a_sH, const float* __restrict__ a_dH,
                           const ushortt* __restrict__ hBH,
                           const float* __restrict__ bnsc, const float* __restrict__ bnsh,
                           ushortt* __restrict__ actb, int N) {
    int hd = blockIdx.x & 3;
    int node = (blockIdx.x >> 2) * 4 + (threadIdx.x >> 6);
    int lane = threadIdx.x & 63;
    if (node >= N) return;
    int grp = lane >> 3, sub = lane & 7;
    unsigned subb = (unsigned)(sub * 16);
    int beg = off[node], end = off[node + 1], deg = end - beg;
    const float* asp = a_sH + (size_t)hd * N;
    float ad = a_dH[(size_t)hd * N + node];
    const char* hBb = (const char*)(hBH + (size_t)hd * N * 64);
    float acc[8] = {};
    float ssum = 0.f;
    int nt = (deg + 7) >> 3;
    int j = beg + grp;
    int t = 0;
    for (; t + 2 <= nt; t += 2, j += 16) {
        int jA = j, jB = j + 8;
        bool vA = jA < end, vB = jB < end;
        int iA = vA ? jA : beg, iB = vB ? jB : beg;
        int sA = csr[iA], sB = csr[iB];
        float wA = asp[sA] + ad; wA = wA > 0.f ? wA : NEG_SLOPE * wA;
        float wB = asp[sB] + ad; wB = wB > 0.f ? wB : NEG_SLOPE * wB;
        float aA = vA ? __expf(wA) : 0.f;
        float aB = vB ? __expf(wB) : 0.f;
        uint4 hA = *(const uint4*)(hBb + (unsigned)sA * 128u + subb);
        uint4 hBv = *(const uint4*)(hBb + (unsigned)sB * 128u + subb);
        acc8(acc, aA, hA);
        acc8(acc, aB, hBv);
        ssum += aA + aB;
    }
    for (; t < nt; ++t, j += 8) {
        bool v = j < end;
        int idx = v ? j : beg;
        int s = csr[idx];
        float w = asp[s] + ad; w = w > 0.f ? w : NEG_SLOPE * w;
        float a = v ? __expf(w) : 0.f;
        uint4 h = *(const uint4*)(hBb + (unsigned)s * 128u + subb);
        acc8(acc, a, h);
        ssum += a;
    }
    #pragma unroll
    for (int o = 8; o <= 32; o <<= 1) {
        #pragma unroll
        for (int i = 0; i < 8; ++i) acc[i] += __shfl_xor(acc[i], o);
        ssum += __shfl_xor(ssum, o);
    }
    if (lane < 8) {
        float inv = 1.f / (ssum + 1e-16f);
        int gc = hd * 64 + lane * 8;
        float o[8];
        #pragma unroll
        for (int i = 0; i < 8; ++i) {
            float v = acc[i] * inv * bnsc[gc + i] + bnsh[gc + i];
            o[i] = v > 0.f ? v : expm1f(v);
        }
        uint4 pk = make_uint4(pack2bf(o[0], o[1]), pack2bf(o[2], o[3]),
                              pack2bf(o[4], o[5]), pack2bf(o[6], o[7]));
        *(uint4*)&actb[(size_t)node * 256 + gc] = pk;
    }
}

// ---------------- PV layer 2: wave=node, 8 lanes/edge; BN+ELU -> bf16 act2 ----------------
__launch_bounds__(256)
__global__ void pv2_kernel(const int* __restrict__ off, const int* __restrict__ csr,
                           const float* __restrict__ a_s, const float* __restrict__ a_d,
                           const ushortt* __restrict__ hB,
                           const float* __restrict__ bnsc, const float* __restrict__ bnsh,
                           ushortt* __restrict__ act2b, int N) {
    int node = blockIdx.x * 4 + (threadIdx.x >> 6);
    int lane = threadIdx.x & 63;
    if (node >= N) return;
    int grp = lane >> 3, sub = lane & 7;
    unsigned subb = (unsigned)(sub * 16);
    int beg = off[node], end = off[node + 1], deg = end - beg;
    float ad = a_d[node];
    const char* hBb = (const char*)hB;
    float acc[8] = {};
    float ssum = 0.f;
    int nt = (deg + 7) >> 3;
    int j = beg + grp;
    int t = 0;
    for (; t + 2 <= nt; t += 2, j += 16) {
        int jA = j, jB = j + 8;
        bool vA = jA < end, vB = jB < end;
        int iA = vA ? jA : beg, iB = vB ? jB : beg;
        int sA = csr[iA], sB = csr[iB];
        float wA = a_s[sA] + ad; wA = wA > 0.f ? wA : NEG_SLOPE * wA;
        float wB = a_s[sB] + ad; wB = wB > 0.f ? wB : NEG_SLOPE * wB;
        float aA = vA ? __expf(wA) : 0.f;
        float aB = vB ? __expf(wB) : 0.f;
        uint4 hA = *(const uint4*)(hBb + (unsigned)sA * 128u + subb);
        uint4 hBv = *(const uint4*)(hBb + (unsigned)sB * 128u + subb);
        acc8(acc, aA, hA);
        acc8(acc, aB, hBv);
        ssum += aA + aB;
    }
    for (; t < nt; ++t, j += 8) {
        bool v = j < end;
        int idx = v ? j : beg;
        int s = csr[idx];
        float w = a_s[s] + ad; w = w > 0.f ? w : NEG_SLOPE * w;
        float a = v ? __expf(w) : 0.f;
        uint4 h = *(const uint4*)(hBb + (unsigned)s * 128u + subb);
        acc8(acc, a, h);
        ssum += a;
    }
    #pragma unroll
    for (int o = 8; o <= 32; o <<= 1) {
        #pragma unroll
        for (int i = 0; i < 8; ++i) acc[i] += __shfl_xor(acc[i], o);
        ssum += __shfl_xor(ssum, o);
    }
    if (lane < 8) {
        float inv = 1.f / (ssum + 1e-16f);
        int g = lane * 8;
        float o[8];
        #pragma unroll
        for (int i = 0; i < 8; ++i) {
            float v = acc[i] * inv * bnsc[256 + g + i] + bnsh[256 + g + i];
            o[i] = v > 0.f ? v : expm1f(v);
        }
        uint4 pk = make_uint4(pack2bf(o[0], o[1]), pack2bf(o[2], o[3]),
                              pack2bf(o[4], o[5]), pack2bf(o[6], o[7]));
        *(uint4*)&act2b[(size_t)node * 64 + g] = pk;
    }
}

// ---------------- PV layer 3: wave=node; fused bias + log_softmax -> out ----------------
__launch_bounds__(256)
__global__ void pv3_kernel(const int* __restrict__ off, const int* __restrict__ csr,
                           const float* __restrict__ a_s, const float* __restrict__ a_d,
                           const ushortt* __restrict__ hB, const float* __restrict__ bias,
                           float* __restrict__ out, int N) {
    int node = blockIdx.x * 4 + (threadIdx.x >> 6);
    int lane = threadIdx.x & 63;
    if (node >= N) return;
    int grp = lane >> 3, sub = lane & 7;
    unsigned subb = (unsigned)(sub * 16);
    int beg = off[node], end = off[node + 1];
    float ad = a_d[node];
    const char* hBb = (const char*)hB;
    float acc[8] = {};
    float ssum = 0.f;
    for (int j0 = beg; j0 < end; j0 += 8) {
        int j = j0 + grp;
        bool v = j < end;
        int idx = v ? j : beg;
        int s = csr[idx];
        float w = a_s[s] + ad; w = w > 0.f ? w : NEG_SLOPE * w;
        float a = v ? __expf(w) : 0.f;
        uint4 h = *(const uint4*)(hBb + (unsigned)s * 128u + subb);
        acc8(acc, a, h);
        ssum += a;
    }
    #pragma unroll
    for (int o = 8; o <= 32; o <<= 1) {
        #pragma unroll
        for (int i = 0; i < 8; ++i) acc[i] += __shfl_xor(acc[i], o);
        ssum += __shfl_xor(ssum, o);
    }
    float inv = 1.f / (ssum + 1e-16f);
    int g = lane * 8;
    bool act8 = lane < 5;
    float val[8];
    float mx = -INFINITY;
    #pragma unroll
    for (int i = 0; i < 8; ++i) {
        val[i] = act8 ? (acc[i] * inv + bias[act8 ? (g + i) : 0]) : -INFINITY;
        mx = fmaxf(mx, val[i]);
    }
    #pragma unroll
    for (int o = 1; o < 8; o <<= 1) mx = fmaxf(mx, __shfl_xor(mx, o));
    float se = 0.f;
    if (act8) {
        #pragma unroll
        for (int i = 0; i < 8; ++i) se += __expf(val[i] - mx);
    }
    #pragma unroll
    for (int o = 1; o < 8; o <<= 1) se += __shfl_xor(se, o);
    if (act8) {
        float lse = mx + logf(se);
        float* dst = &out[(size_t)node * 40 + g];
        fx4 v0 = {val[0] - lse, val[1] - lse, val[2] - lse, val[3] - lse};
        fx4 v1 = {val[4] - lse, val[5] - lse, val[6] - lse, val[7] - lse};
        *(fx4*)dst = v0;
        *(fx4*)(dst + 4) = v1;
    }
}

// ---------------- host ----------------
extern "C" void kernel_launch(void* const* d_in, const int* in_sizes, int n_in,
                              void* d_out, int out_size, void* d_ws, size_t ws_size,
                              hipStream_t stream) {
    const float* x      = (const float*)d_in[0];
    const int*   ei     = (const int*)d_in[1];
    const float* W1     = (const float*)d_in[2];
    const float* att_s1 = (const float*)d_in[3];
    const float* att_d1 = (const float*)d_in[4];
    const float* b1     = (const float*)d_in[5];
    const float* bn1g   = (const float*)d_in[6];
    const float* bn1b   = (const float*)d_in[7];
    const float* bn1m   = (const float*)d_in[8];
    const float* bn1v   = (const float*)d_in[9];
    const float* W2     = (const float*)d_in[10];
    const float* att_s2 = (const float*)d_in[11];
    const float* att_d2 = (const float*)d_in[12];
    const float* b2     = (const float*)d_in[13];
    const float* bn2g   = (const float*)d_in[14];
    const float* bn2b   = (const float*)d_in[15];
    const float* bn2m   = (const float*)d_in[16];
    const float* bn2v   = (const float*)d_in[17];
    const float* W3     = (const float*)d_in[18];
    const float* att_s3 = (const float*)d_in[19];
    const float* att_d3 = (const float*)d_in[20];
    const float* b3     = (const float*)d_in[21];

    const int N    = in_sizes[0] / IN_DIM;
    const int E    = in_sizes[1] / 2;
    const int Etot = E + N;

    int*   wsi = (int*)d_ws;
    float* wsf = (float*)d_ws;
    size_t p = 0;
    int*   off    = wsi + p; p += (size_t)N + 16;
    int*   cursor = wsi + p; p += (size_t)N;
    int*   flag   = wsi + p; p += 16;
    int*   csr    = wsi + p; p += (size_t)Etot;
    float* a_sH   = wsf + p; p += (size_t)N * 4;
    float* a_dH   = wsf + p; p += (size_t)N * 4;
    float* bnsc   = wsf + p; p += 384;
    float* bnsh   = wsf + p; p += 384;
    size_t H = p;            p += (size_t)N * 128;   // hB1H (head-major) / hB23
    size_t A1 = p;           p += (size_t)N * 128;   // actb  (N*256 bf16)
    size_t A2 = p;           p += (size_t)N * 32;    // act2b (N*64 bf16)
    if (ws_size < p * 4) return;

    ushortt* hB1H  = (ushortt*)(wsf + H);
    ushortt* hB23  = (ushortt*)(wsf + H);
    ushortt* actb  = (ushortt*)(wsf + A1);
    ushortt* act2b = (ushortt*)(wsf + A2);

    float* outp = (float*)d_out;

    // ---- CSR build ----
    hipMemsetAsync(off, 0, ((size_t)N + 1) * sizeof(int), stream);
    detect_kernel<<<1, 256, 0, stream>>>((const unsigned int*)ei, flag);
    {
        int blocks = (Etot + 255) / 256;
        hist_kernel<<<blocks, 256, 0, stream>>>(ei, flag, off, E, Etot);
        scan_kernel<<<1, 1024, 0, stream>>>(off, N + 1);
        hipMemcpyAsync(cursor, off, (size_t)N * sizeof(int), hipMemcpyDeviceToDevice, stream);
        scatter_kernel<<<blocks, 256, 0, stream>>>(ei, flag, cursor, csr, E, Etot);
    }
    prep_bn_kernel<<<1, 384, 0, stream>>>(b1, bn1g, bn1b, bn1m, bn1v,
                                          b2, bn2g, bn2b, bn2m, bn2v, bnsc, bnsh);

    const int gm = (N + 127) / 128;
    const int nb4 = (N + 3) / 4;

    // ---- layer 1 ----
    gemm_fused_kernel<128, 128, 8, 256, 256, false, true>
        <<<dim3(gm, 2), 256, 0, stream>>>(x, W1, hB1H, att_s1, att_d1, a_sH, a_dH, N, N);
    pv1_kernel<<<nb4 * 4, 256, 0, stream>>>(off, csr, a_sH, a_dH, hB1H, bnsc, bnsh, actb, N);

    // ---- layer 2 ----
    gemm_fused_kernel<256, 64, 4, 64, 64, true, false>
        <<<dim3(gm, 1), 256, 0, stream>>>(actb, W2, hB23, att_s2, att_d2, a_sH, a_dH, N, N);
    pv2_kernel<<<nb4, 256, 0, stream>>>(off, csr, a_sH, a_dH, hB23, bnsc, bnsh, act2b, N);

    // ---- layer 3 (log_softmax fused into PV epilogue) ----
    gemm_fused_kernel<64, 64, 4, 40, 40, true, false>
        <<<dim3(gm, 1), 256, 0, stream>>>(act2b, W3, hB23, att_s3, att_d3, a_sH, a_dH, N, N);
    pv3_kernel<<<nb4, 256, 0, stream>>>(off, csr, a_sH, a_dH, hB23, b3, outp, N);
}

// Round 11
// 786.847 us; speedup vs baseline: 2.5964x; 1.1630x over previous
//
#include <hip/hip_runtime.h>
#include <cstdint>

#define IN_DIM   128
#define HIDC     64
#define HEADS    4
#define OUT_DIM  40
#define NEG_SLOPE 0.2f
#define BN_EPS   1e-5f

typedef unsigned short ushortt;
typedef float fx4 __attribute__((ext_vector_type(4)));

__device__ __forceinline__ float bfval(ushortt u) {
    return __uint_as_float(((unsigned)u) << 16);
}
__device__ __forceinline__ ushortt f2bf(float f) {
    unsigned u = __float_as_uint(f);
    u += 0x7fffu + ((u >> 16) & 1u);
    return (ushortt)(u >> 16);
}
__device__ __forceinline__ unsigned pack2bf(float a, float b) {
    return (unsigned)f2bf(a) | ((unsigned)f2bf(b) << 16);
}

// acc[0..7] += a * bf16x8(h)
__device__ __forceinline__ void acc8(float* acc, float a, uint4 h) {
    unsigned u;
    u = h.x;
    acc[0] = fmaf(a, __uint_as_float(u << 16), acc[0]);
    acc[1] = fmaf(a, __uint_as_float(u & 0xffff0000u), acc[1]);
    u = h.y;
    acc[2] = fmaf(a, __uint_as_float(u << 16), acc[2]);
    acc[3] = fmaf(a, __uint_as_float(u & 0xffff0000u), acc[3]);
    u = h.z;
    acc[4] = fmaf(a, __uint_as_float(u << 16), acc[4]);
    acc[5] = fmaf(a, __uint_as_float(u & 0xffff0000u), acc[5]);
    u = h.w;
    acc[6] = fmaf(a, __uint_as_float(u << 16), acc[6]);
    acc[7] = fmaf(a, __uint_as_float(u & 0xffff0000u), acc[7]);
}

// ---------------- CSR build ----------------
__global__ void detect_kernel(const unsigned int* __restrict__ e, int* __restrict__ flag) {
    __shared__ int any;
    if (threadIdx.x == 0) any = 0;
    __syncthreads();
    for (int i = threadIdx.x; i < 1024; i += 256)
        if (e[2 * i + 1] != 0u) any = 1;
    __syncthreads();
    if (threadIdx.x == 0) flag[0] = any ? 0 : 1;   // 1 => int64
}

__device__ __forceinline__ int load_idx(const int* ei, int is64, long long pos) {
    return is64 ? ei[2 * pos] : ei[pos];
}

__global__ void hist_kernel(const int* __restrict__ ei, const int* __restrict__ flag,
                            int* __restrict__ deg, int E, int Etot) {
    int i = blockIdx.x * 256 + threadIdx.x;
    if (i >= Etot) return;
    int is64 = flag[0];
    int dst = (i < E) ? load_idx(ei, is64, (long long)E + i) : (i - E);
    atomicAdd(&deg[dst], 1);
}

__global__ void scan_kernel(int* __restrict__ data, int n) {
    __shared__ int wsum[16];
    __shared__ int chunk_total;
    int lane = threadIdx.x & 63;
    int w = threadIdx.x >> 6;
    int carry = 0;
    for (int base = 0; base < n; base += 1024) {
        int i = base + (int)threadIdx.x;
        int v = (i < n) ? data[i] : 0;
        int x = v;
        #pragma unroll
        for (int ofs = 1; ofs < 64; ofs <<= 1) {
            int y = __shfl_up(x, ofs);
            if (lane >= ofs) x += y;
        }
        if (lane == 63) wsum[w] = x;
        __syncthreads();
        if (w == 0) {
            int s = (lane < 16) ? wsum[lane] : 0;
            #pragma unroll
            for (int ofs = 1; ofs < 16; ofs <<= 1) {
                int y = __shfl_up(s, ofs);
                if (lane >= ofs) s += y;
            }
            if (lane < 16) wsum[lane] = s;
            if (lane == 15) chunk_total = s;
        }
        __syncthreads();
        int woff = (w > 0) ? wsum[w - 1] : 0;
        if (i < n) data[i] = (x + woff) - v + carry;
        int ct = chunk_total;
        __syncthreads();
        carry += ct;
    }
}

__global__ void scatter_kernel(const int* __restrict__ ei, const int* __restrict__ flag,
                               int* __restrict__ cursor, int* __restrict__ csr,
                               int* __restrict__ dstv, int E, int Etot) {
    int i = blockIdx.x * 256 + threadIdx.x;
    if (i >= Etot) return;
    int is64 = flag[0];
    int src, dst;
    if (i < E) {
        src = load_idx(ei, is64, i);
        dst = load_idx(ei, is64, (long long)E + i);
    } else {
        src = dst = i - E;
    }
    int pos = atomicAdd(&cursor[dst], 1);
    csr[pos] = src;
    dstv[pos] = dst;
}

// ---------------- fold bias+BN into scale/shift ----------------
__global__ void prep_bn_kernel(const float* b1, const float* g1, const float* bb1,
                               const float* m1, const float* v1,
                               const float* b2, const float* g2, const float* bb2,
                               const float* m2, const float* v2,
                               float* __restrict__ bnsc, float* __restrict__ bnsh) {
    int t = threadIdx.x;
    if (t < 256) {
        float s = g1[t] * rsqrtf(v1[t] + BN_EPS);
        bnsc[t] = s;
        bnsh[t] = (b1[t] - m1[t]) * s + bb1[t];
    } else if (t < 320) {
        int c = t - 256;
        float s = g2[c] * rsqrtf(v2[c] + BN_EPS);
        bnsc[t] = s;
        bnsh[t] = (b2[c] - m2[c]) * s + bb2[c];
    }
}

// ---------------- register-tiled GEMM + fused attention dots -> bf16 h ----------------
// L1MODE: h row-major [node][256]; a_s4/a_d4 node-major [node*4+head].
// else:   h row-major [node][64]; a_s[node], a_d[node].
template <int K, int BN, int TN, int NC, int LDW, bool ABF16, bool L1MODE>
__launch_bounds__(256)
__global__ void gemm_fused_kernel(const void* __restrict__ Av, const float* __restrict__ W,
                                  ushortt* __restrict__ hB,
                                  const float* __restrict__ atts, const float* __restrict__ attd,
                                  float* __restrict__ a_s, float* __restrict__ a_d, int M) {
    __shared__ float Al[8][128];
    __shared__ float Wl[8][BN];
    int m0 = blockIdx.x * 128;
    int n0 = blockIdx.y * BN;
    int t = threadIdx.x;
    int tm = t >> 4, tn = t & 15;
    float acc[8][TN] = {};
    int r = t >> 1, kq = (t & 1) * 4;

    for (int k0 = 0; k0 < K; k0 += 8) {
        if constexpr (ABF16) {
            const ushortt* A = (const ushortt*)Av;
            uint2 av = make_uint2(0u, 0u);
            if (m0 + r < M) av = *(const uint2*)(A + (size_t)(m0 + r) * K + k0 + kq);
            Al[kq + 0][r] = bfval((ushortt)(av.x & 0xffffu));
            Al[kq + 1][r] = bfval((ushortt)(av.x >> 16));
            Al[kq + 2][r] = bfval((ushortt)(av.y & 0xffffu));
            Al[kq + 3][r] = bfval((ushortt)(av.y >> 16));
        } else {
            const float* A = (const float*)Av;
            float4 av = make_float4(0.f, 0.f, 0.f, 0.f);
            if (m0 + r < M) av = *(const float4*)&A[(size_t)(m0 + r) * K + k0 + kq];
            Al[kq + 0][r] = av.x; Al[kq + 1][r] = av.y;
            Al[kq + 2][r] = av.z; Al[kq + 3][r] = av.w;
        }
        if constexpr (BN == 128) {
            int kk = t >> 5, c4 = (t & 31) * 4;
            *(float4*)&Wl[kk][c4] = *(const float4*)&W[(size_t)(k0 + kk) * LDW + n0 + c4];
        } else {
            int kk = t >> 5, c2 = (t & 31) * 2;
            float2 wv = make_float2(0.f, 0.f);
            if (c2 + 2 <= NC) wv = *(const float2*)&W[(size_t)(k0 + kk) * LDW + n0 + c2];
            *(float2*)&Wl[kk][c2] = wv;
        }
        __syncthreads();
        #pragma unroll
        for (int k = 0; k < 8; ++k) {
            float4 a0 = *(const float4*)&Al[k][tm * 8];
            float4 a1 = *(const float4*)&Al[k][tm * 8 + 4];
            float aa[8] = {a0.x, a0.y, a0.z, a0.w, a1.x, a1.y, a1.z, a1.w};
            if constexpr (TN == 8) {
                float4 w0 = *(const float4*)&Wl[k][tn * 4];
                float4 w1 = *(const float4*)&Wl[k][64 + tn * 4];
                float ww[8] = {w0.x, w0.y, w0.z, w0.w, w1.x, w1.y, w1.z, w1.w};
                #pragma unroll
                for (int i = 0; i < 8; ++i)
                    #pragma unroll
                    for (int j = 0; j < 8; ++j)
                        acc[i][j] = fmaf(aa[i], ww[j], acc[i][j]);
            } else {
                float4 w0 = *(const float4*)&Wl[k][tn * 4];
                float ww[4] = {w0.x, w0.y, w0.z, w0.w};
                #pragma unroll
                for (int i = 0; i < 8; ++i)
                    #pragma unroll
                    for (int j = 0; j < 4; ++j)
                        acc[i][j] = fmaf(aa[i], ww[j], acc[i][j]);
            }
        }
        __syncthreads();
    }
    // ---- epilogue: bf16 stores + fused per-row attention dots ----
    #pragma unroll
    for (int i = 0; i < 8; ++i) {
        int m = m0 + tm * 8 + i;
        bool valid = m < M;
        if constexpr (L1MODE) {
            int h0 = n0 >> 6;
            if (valid) {
                ushortt* row = hB + (size_t)m * 256 + n0;
                *(uint2*)(row + tn * 4) = make_uint2(pack2bf(acc[i][0], acc[i][1]),
                                                     pack2bf(acc[i][2], acc[i][3]));
                *(uint2*)(row + 64 + tn * 4) = make_uint2(pack2bf(acc[i][4], acc[i][5]),
                                                          pack2bf(acc[i][6], acc[i][7]));
            }
            int c0 = n0 + tn * 4, c1 = c0 + 64;
            float ps0 = acc[i][0] * atts[c0] + acc[i][1] * atts[c0 + 1]
                      + acc[i][2] * atts[c0 + 2] + acc[i][3] * atts[c0 + 3];
            float pd0 = acc[i][0] * attd[c0] + acc[i][1] * attd[c0 + 1]
                      + acc[i][2] * attd[c0 + 2] + acc[i][3] * attd[c0 + 3];
            float ps1 = acc[i][4] * atts[c1] + acc[i][5] * atts[c1 + 1]
                      + acc[i][6] * atts[c1 + 2] + acc[i][7] * atts[c1 + 3];
            float pd1 = acc[i][4] * attd[c1] + acc[i][5] * attd[c1 + 1]
                      + acc[i][6] * attd[c1 + 2] + acc[i][7] * attd[c1 + 3];
            #pragma unroll
            for (int o = 1; o < 16; o <<= 1) {
                ps0 += __shfl_xor(ps0, o); pd0 += __shfl_xor(pd0, o);
                ps1 += __shfl_xor(ps1, o); pd1 += __shfl_xor(pd1, o);
            }
            if (tn == 0 && valid) {
                a_s[(size_t)m * 4 + h0]     = ps0;
                a_s[(size_t)m * 4 + h0 + 1] = ps1;
                a_d[(size_t)m * 4 + h0]     = pd0;
                a_d[(size_t)m * 4 + h0 + 1] = pd1;
            }
        } else {
            if (valid) {
                ushortt* row = hB + (size_t)m * 64 + tn * 4;
                *(uint2*)row = make_uint2(pack2bf(acc[i][0], acc[i][1]),
                                          pack2bf(acc[i][2], acc[i][3]));
            }
            float ps = 0.f, pd = 0.f;
            #pragma unroll
            for (int j = 0; j < 4; ++j) {
                int c = tn * 4 + j;
                float as = (c < NC) ? atts[c] : 0.f;
                float ad = (c < NC) ? attd[c] : 0.f;
                ps = fmaf(acc[i][j], as, ps);
                pd = fmaf(acc[i][j], ad, pd);
            }
            #pragma unroll
            for (int o = 1; o < 16; o <<= 1) {
                ps += __shfl_xor(ps, o); pd += __shfl_xor(pd, o);
            }
            if (tn == 0 && valid) { a_s[m] = ps; a_d[m] = pd; }
        }
    }
}

// ---------------- alpha layer 1: edge-parallel, 4 heads -> alH[h*Etot + j] fp32 ----------------
__launch_bounds__(256)
__global__ void alpha4e_kernel(const int* __restrict__ csr, const int* __restrict__ dstv,
                               const float* __restrict__ a_s4, const float* __restrict__ a_d4,
                               float* __restrict__ alH, int Etot) {
    int j = blockIdx.x * 256 + threadIdx.x;
    if (j >= Etot) return;
    int s = csr[j], d = dstv[j];
    fx4 as = *(const fx4*)&a_s4[(size_t)s * 4];
    fx4 ad = *(const fx4*)&a_d4[(size_t)d * 4];
    #pragma unroll
    for (int h = 0; h < 4; ++h) {
        float v = as[h] + ad[h];
        v = v > 0.f ? v : NEG_SLOPE * v;
        alH[(size_t)h * Etot + j] = __expf(v);
    }
}

// ---------------- PV layer 1: wave=node, 2 edges/step, 32 lanes/edge, unroll 4 ----------------
// Reads fp32 unnormalized alpha (per-head streams); accumulates per-head ssum in-walk.
__launch_bounds__(256)
__global__ void pv1_kernel(const int* __restrict__ off, const int* __restrict__ csr,
                           const float* __restrict__ alH, const ushortt* __restrict__ hB,
                           const float* __restrict__ bnsc, const float* __restrict__ bnsh,
                           ushortt* __restrict__ actb, int N, int Etot) {
    int node = blockIdx.x * 4 + (threadIdx.x >> 6);
    int lane = threadIdx.x & 63;
    if (node >= N) return;
    int half = lane >> 5, sub = lane & 31, head = sub >> 3;
    unsigned subb = (unsigned)(sub * 16);
    int beg = off[node], end = off[node + 1], deg = end - beg;
    const float* alh = alH + (size_t)head * Etot;
    const char* hBb = (const char*)hB;
    float acc[8] = {};
    float ssum = 0.f;
    int nt = (deg + 1) >> 1;
    int j = beg + half;
    int t = 0;
    for (; t + 4 <= nt; t += 4, j += 8) {
        float av[4]; unsigned ro[4];
        #pragma unroll
        for (int q = 0; q < 4; ++q) {
            int jq = j + 2 * q;
            bool v = jq < end;
            int idx = v ? jq : beg;
            int s = csr[idx];
            av[q] = v ? alh[idx] : 0.f;
            ro[q] = (unsigned)s * 512u + subb;
        }
        uint4 h0 = *(const uint4*)(hBb + ro[0]);
        uint4 h1 = *(const uint4*)(hBb + ro[1]);
        uint4 h2 = *(const uint4*)(hBb + ro[2]);
        uint4 h3 = *(const uint4*)(hBb + ro[3]);
        acc8(acc, av[0], h0);
        acc8(acc, av[1], h1);
        acc8(acc, av[2], h2);
        acc8(acc, av[3], h3);
        ssum += (av[0] + av[1]) + (av[2] + av[3]);
    }
    for (; t < nt; ++t, j += 2) {
        bool v = j < end;
        int idx = v ? j : beg;
        int s = csr[idx];
        float a = v ? alh[idx] : 0.f;
        uint4 h = *(const uint4*)(hBb + (unsigned)s * 512u + subb);
        acc8(acc, a, h);
        ssum += a;
    }
    #pragma unroll
    for (int i = 0; i < 8; ++i) acc[i] += __shfl_xor(acc[i], 32);
    ssum += __shfl_xor(ssum, 32);
    if (half == 0) {
        float inv = 1.f / (ssum + 1e-16f);
        int g = sub * 8;
        float o[8];
        #pragma unroll
        for (int i = 0; i < 8; ++i) {
            float v = acc[i] * inv * bnsc[g + i] + bnsh[g + i];
            o[i] = v > 0.f ? v : expm1f(v);
        }
        uint4 pk = make_uint4(pack2bf(o[0], o[1]), pack2bf(o[2], o[3]),
                              pack2bf(o[4], o[5]), pack2bf(o[6], o[7]));
        *(uint4*)&actb[(size_t)node * 256 + g] = pk;
    }
}

// ---------------- PV layer 2: wave=node, 8 lanes/edge, inline exp; BN+ELU -> bf16 act2 ----------------
__launch_bounds__(256)
__global__ void pv2_kernel(const int* __restrict__ off, const int* __restrict__ csr,
                           const float* __restrict__ a_s, const float* __restrict__ a_d,
                           const ushortt* __restrict__ hB,
                           const float* __restrict__ bnsc, const float* __restrict__ bnsh,
                           ushortt* __restrict__ act2b, int N) {
    int node = blockIdx.x * 4 + (threadIdx.x >> 6);
    int lane = threadIdx.x & 63;
    if (node >= N) return;
    int grp = lane >> 3, sub = lane & 7;
    unsigned subb = (unsigned)(sub * 16);
    int beg = off[node], end = off[node + 1], deg = end - beg;
    float ad = a_d[node];
    const char* hBb = (const char*)hB;
    float acc[8] = {};
    float ssum = 0.f;
    int nt = (deg + 7) >> 3;
    int j = beg + grp;
    int t = 0;
    for (; t + 2 <= nt; t += 2, j += 16) {
        int jA = j, jB = j + 8;
        bool vA = jA < end, vB = jB < end;
        int iA = vA ? jA : beg, iB = vB ? jB : beg;
        int sA = csr[iA], sB = csr[iB];
        float wA = a_s[sA] + ad; wA = wA > 0.f ? wA : NEG_SLOPE * wA;
        float wB = a_s[sB] + ad; wB = wB > 0.f ? wB : NEG_SLOPE * wB;
        float aA = vA ? __expf(wA) : 0.f;
        float aB = vB ? __expf(wB) : 0.f;
        uint4 hA = *(const uint4*)(hBb + (unsigned)sA * 128u + subb);
        uint4 hBv = *(const uint4*)(hBb + (unsigned)sB * 128u + subb);
        acc8(acc, aA, hA);
        acc8(acc, aB, hBv);
        ssum += aA + aB;
    }
    for (; t < nt; ++t, j += 8) {
        bool v = j < end;
        int idx = v ? j : beg;
        int s = csr[idx];
        float w = a_s[s] + ad; w = w > 0.f ? w : NEG_SLOPE * w;
        float a = v ? __expf(w) : 0.f;
        uint4 h = *(const uint4*)(hBb + (unsigned)s * 128u + subb);
        acc8(acc, a, h);
        ssum += a;
    }
    #pragma unroll
    for (int o = 8; o <= 32; o <<= 1) {
        #pragma unroll
        for (int i = 0; i < 8; ++i) acc[i] += __shfl_xor(acc[i], o);
        ssum += __shfl_xor(ssum, o);
    }
    if (lane < 8) {
        float inv = 1.f / (ssum + 1e-16f);
        int g = lane * 8;
        float o[8];
        #pragma unroll
        for (int i = 0; i < 8; ++i) {
            float v = acc[i] * inv * bnsc[256 + g + i] + bnsh[256 + g + i];
            o[i] = v > 0.f ? v : expm1f(v);
        }
        uint4 pk = make_uint4(pack2bf(o[0], o[1]), pack2bf(o[2], o[3]),
                              pack2bf(o[4], o[5]), pack2bf(o[6], o[7]));
        *(uint4*)&act2b[(size_t)node * 64 + g] = pk;
    }
}

// ---------------- PV layer 3: wave=node; fused bias + log_softmax -> out ----------------
__launch_bounds__(256)
__global__ void pv3_kernel(const int* __restrict__ off, const int* __restrict__ csr,
                           const float* __restrict__ a_s, const float* __restrict__ a_d,
                           const ushortt* __restrict__ hB, const float* __restrict__ bias,
                           float* __restrict__ out, int N) {
    int node = blockIdx.x * 4 + (threadIdx.x >> 6);
    int lane = threadIdx.x & 63;
    if (node >= N) return;
    int grp = lane >> 3, sub = lane & 7;
    unsigned subb = (unsigned)(sub * 16);
    int beg = off[node], end = off[node + 1];
    float ad = a_d[node];
    const char* hBb = (const char*)hB;
    float acc[8] = {};
    float ssum = 0.f;
    for (int j0 = beg; j0 < end; j0 += 8) {
        int j = j0 + grp;
        bool v = j < end;
        int idx = v ? j : beg;
        int s = csr[idx];
        float w = a_s[s] + ad; w = w > 0.f ? w : NEG_SLOPE * w;
        float a = v ? __expf(w) : 0.f;
        uint4 h = *(const uint4*)(hBb + (unsigned)s * 128u + subb);
        acc8(acc, a, h);
        ssum += a;
    }
    #pragma unroll
    for (int o = 8; o <= 32; o <<= 1) {
        #pragma unroll
        for (int i = 0; i < 8; ++i) acc[i] += __shfl_xor(acc[i], o);
        ssum += __shfl_xor(ssum, o);
    }
    float inv = 1.f / (ssum + 1e-16f);
    int g = lane * 8;
    bool act8 = lane < 5;
    float val[8];
    float mx = -INFINITY;
    #pragma unroll
    for (int i = 0; i < 8; ++i) {
        val[i] = act8 ? (acc[i] * inv + bias[act8 ? (g + i) : 0]) : -INFINITY;
        mx = fmaxf(mx, val[i]);
    }
    #pragma unroll
    for (int o = 1; o < 8; o <<= 1) mx = fmaxf(mx, __shfl_xor(mx, o));
    float se = 0.f;
    if (act8) {
        #pragma unroll
        for (int i = 0; i < 8; ++i) se += __expf(val[i] - mx);
    }
    #pragma unroll
    for (int o = 1; o < 8; o <<= 1) se += __shfl_xor(se, o);
    if (act8) {
        float lse = mx + logf(se);
        float* dst = &out[(size_t)node * 40 + g];
        fx4 v0 = {val[0] - lse, val[1] - lse, val[2] - lse, val[3] - lse};
        fx4 v1 = {val[4] - lse, val[5] - lse, val[6] - lse, val[7] - lse};
        *(fx4*)dst = v0;
        *(fx4*)(dst + 4) = v1;
    }
}

// ---------------- host ----------------
extern "C" void kernel_launch(void* const* d_in, const int* in_sizes, int n_in,
                              void* d_out, int out_size, void* d_ws, size_t ws_size,
                              hipStream_t stream) {
    const float* x      = (const float*)d_in[0];
    const int*   ei     = (const int*)d_in[1];
    const float* W1     = (const float*)d_in[2];
    const float* att_s1 = (const float*)d_in[3];
    const float* att_d1 = (const float*)d_in[4];
    const float* b1     = (const float*)d_in[5];
    const float* bn1g   = (const float*)d_in[6];
    const float* bn1b   = (const float*)d_in[7];
    const float* bn1m   = (const float*)d_in[8];
    const float* bn1v   = (const float*)d_in[9];
    const float* W2     = (const float*)d_in[10];
    const float* att_s2 = (const float*)d_in[11];
    const float* att_d2 = (const float*)d_in[12];
    const float* b2     = (const float*)d_in[13];
    const float* bn2g   = (const float*)d_in[14];
    const float* bn2b   = (const float*)d_in[15];
    const float* bn2m   = (const float*)d_in[16];
    const float* bn2v   = (const float*)d_in[17];
    const float* W3     = (const float*)d_in[18];
    const float* att_s3 = (const float*)d_in[19];
    const float* att_d3 = (const float*)d_in[20];
    const float* b3     = (const float*)d_in[21];

    const int N    = in_sizes[0] / IN_DIM;
    const int E    = in_sizes[1] / 2;
    const int Etot = E + N;

    int*   wsi = (int*)d_ws;
    float* wsf = (float*)d_ws;
    size_t p = 0;
    int*   off    = wsi + p; p += (size_t)N + 16;  p = (p + 3) & ~(size_t)3;
    int*   cursor = wsi + p; p += (size_t)N;       p = (p + 3) & ~(size_t)3;
    int*   flag   = wsi + p; p += 16;
    int*   csr    = wsi + p; p += (size_t)Etot;    p = (p + 3) & ~(size_t)3;
    int*   dstv   = wsi + p; p += (size_t)Etot;    p = (p + 3) & ~(size_t)3;
    float* a_s4   = wsf + p; p += (size_t)N * 4;
    float* a_d4   = wsf + p; p += (size_t)N * 4;
    float* bnsc   = wsf + p; p += 384;
    float* bnsh   = wsf + p; p += 384;
    size_t H = p;            p += (size_t)N * 128;   // hB1 (N*256 bf16) / hB23 (N*64 bf16)
    size_t A1 = p;           p += (size_t)N * 128;   // actb  (N*256 bf16)
    size_t A2 = p;           p += (size_t)N * 32;    // act2b (N*64 bf16)
    float* alH = wsf + p;    p += (size_t)Etot * 4;  // layer-1 alpha, fp32, head-major
    if (ws_size < p * 4) return;

    ushortt* hB1   = (ushortt*)(wsf + H);
    ushortt* hB23  = (ushortt*)(wsf + H);
    ushortt* actb  = (ushortt*)(wsf + A1);
    ushortt* act2b = (ushortt*)(wsf + A2);

    float* outp = (float*)d_out;

    // ---- CSR build ----
    hipMemsetAsync(off, 0, ((size_t)N + 1) * sizeof(int), stream);
    detect_kernel<<<1, 256, 0, stream>>>((const unsigned int*)ei, flag);
    {
        int blocks = (Etot + 255) / 256;
        hist_kernel<<<blocks, 256, 0, stream>>>(ei, flag, off, E, Etot);
        scan_kernel<<<1, 1024, 0, stream>>>(off, N + 1);
        hipMemcpyAsync(cursor, off, (size_t)N * sizeof(int), hipMemcpyDeviceToDevice, stream);
        scatter_kernel<<<blocks, 256, 0, stream>>>(ei, flag, cursor, csr, dstv, E, Etot);
    }
    prep_bn_kernel<<<1, 384, 0, stream>>>(b1, bn1g, bn1b, bn1m, bn1v,
                                          b2, bn2g, bn2b, bn2m, bn2v, bnsc, bnsh);

    const int gm = (N + 127) / 128;
    const int nb4 = (N + 3) / 4;
    const int eb = (Etot + 255) / 256;

    // ---- layer 1 ----
    gemm_fused_kernel<128, 128, 8, 256, 256, false, true>
        <<<dim3(gm, 2), 256, 0, stream>>>(x, W1, hB1, att_s1, att_d1, a_s4, a_d4, N);
    alpha4e_kernel<<<eb, 256, 0, stream>>>(csr, dstv, a_s4, a_d4, alH, Etot);
    pv1_kernel<<<nb4, 256, 0, stream>>>(off, csr, alH, hB1, bnsc, bnsh, actb, N, Etot);

    // ---- layer 2 ----
    gemm_fused_kernel<256, 64, 4, 64, 64, true, false>
        <<<dim3(gm, 1), 256, 0, stream>>>(actb, W2, hB23, att_s2, att_d2, a_s4, a_d4, N);
    pv2_kernel<<<nb4, 256, 0, stream>>>(off, csr, a_s4, a_d4, hB23, bnsc, bnsh, act2b, N);

    // ---- layer 3 (log_softmax fused into PV epilogue) ----
    gemm_fused_kernel<64, 64, 4, 40, 40, true, false>
        <<<dim3(gm, 1), 256, 0, stream>>>(act2b, W3, hB23, att_s3, att_d3, a_s4, a_d4, N);
    pv3_kernel<<<nb4, 256, 0, stream>>>(off, csr, a_s4, a_d4, hB23, b3, outp, N);
}